// Round 5
// baseline (337.220 us; speedup 1.0000x reference)
//
#include <hip/hip_runtime.h>
#include <cstdint>
#include <cstddef>

#define B_ 512
#define W_ 1024
#define L_ 64
#define J_ 8
#define I_ 32
#define O_ 128

// ws layout (floats):
// wcg   : [J][L]        = 512   (holds -2*(1-g)*c)
// w1g   : [J][L]        = 512
// Ag    : [J] (+pad)    = 16
// best  : [J][B][L]     = 262144
// conf  : [B]           = 512
// partial:[64][B][I]    = 1048576
// bpart : [2][J][B][L]  = 524288
// stats : [2][B][J][4]  = 32768

typedef const __attribute__((address_space(1))) void* gas_ptr;
typedef __attribute__((address_space(3))) void* las_ptr;

// ---------------------------------------------------------------- K0
__global__ __launch_bounds__(64) void k0_prep(const float* __restrict__ constants,
    const float* __restrict__ gammas, float* __restrict__ wcg,
    float* __restrict__ w1g, float* __restrict__ Ag)
{
  const int l = threadIdx.x;
  #pragma unroll
  for (int j = 0; j < J_; ++j) {
    float g = gammas[j*L_ + l];
    g = fminf(fmaxf(g, 0.f), 1.f);
    float c = constants[j*L_ + l];
    float w1 = 1.f - g;
    w1g[j*L_ + l] = w1;
    wcg[j*L_ + l] = -2.f * w1 * c;   // fold the -2 of the cross term here
  }
  if (l < J_) {
    float a = 0.f;
    for (int c = 0; c < L_; ++c) {
      float g = gammas[l*L_ + c];
      g = fminf(fmaxf(g, 0.f), 1.f);
      float cc = constants[l*L_ + c];
      a += (1.f - g) * cc * cc;
    }
    Ag[l] = a;
  }
}

// ---------------------------------------------------------------- K12: 64-row chunks,
// v5 (resubmitted — r4 was a broker timeout, experiment never ran):
// QUAD-buffered async global->LDS staging, TRUE prefetch distance 2,
// counted vmcnt(4) (never 0 mid-loop). The ch-loop is fully unrolled so
// buffer selection (ch&3) is a compile-time constant: no rotating
// pointers, no extra live registers (r2's 3-pointer rotation spilled;
// this is the same window without the spill mechanism).
//
// Schedule per chunk ch:
//   top   : stage(ch+2 -> buf[(ch+2)&3])          (ch<6)
//   score : buf[ch&3]  (v1 arithmetic: xq=x*x VGPR-only, each fma has
//           exactly ONE SGPR operand — v4's fused form needed 2 SGPR
//           reads/op and cost a v_mov per pair)
//   es publish: lgkmcnt(0) + barrier  (both in-flight chunks untouched)
//   accum : buf[ch&3] own stripe + es
//   end   : ch<=5: vmcnt(4)  -> retires stage(ch+1), stage(ch+2) stays
//           ch==6: vmcnt(0)  -> retires stage(7)
//           ch==7: lgkm only
//           + barrier
// Hazards: stage(ch+2) writes buf[(ch-2)&3], last read in chunk ch-2,
// whose reads retired before that chunk's end barrier (2 barriers ago).
// Chunk ch's score reads buf staged at top of ch-2, retired by the
// vmcnt(4) at end of ch-1. Epilogue xs-reuse protected by final barrier.
__global__ __launch_bounds__(256, 2) void k12_fused(const float* __restrict__ wm,
    const float* __restrict__ wcg, const float* __restrict__ w1g,
    const float* __restrict__ Ag, float* __restrict__ bpart, float* __restrict__ stats)
{
  __shared__ __align__(16) float xs[4][64 * 64];   // 65536 B
  __shared__ __align__(16) float es[J_ * 64];      // 2048 B

  const int tid = threadIdx.x;
  const int b = blockIdx.x, h = blockIdx.y;
  const int lane = tid & 63;
  const int wvu = __builtin_amdgcn_readfirstlane(tid >> 6);  // wave id (uniform)
  const int j0  = wvu * 2;                                   // this wave's j-pair
  const int lq = tid & 15, wsl = tid >> 4;                   // accum mapping
  const int wm15 = lane & 15;                                // score swizzle key
  const int rl = lane >> 4, pcg = lane & 15;                 // staging decomposition

  const float* wmb = wm + (size_t)b * (W_*L_) + (size_t)h * (512*L_);

  float accb[J_][4];
  #pragma unroll
  for (int j = 0; j < J_; ++j)
    #pragma unroll
    for (int q = 0; q < 4; ++q) accb[j][q] = 0.f;
  float esum[2] = {0.f, 0.f}, msum[2] = {0.f, 0.f}, m0v[2];

  auto stage = [&](const float* csrc, float* ldst) {
    #pragma unroll
    for (int k = 0; k < 4; ++k) {
      const int grow = wvu*16 + k*4 + rl;
      const int lcg  = pcg ^ (k*4 + rl);         // (grow&15) == k*4+rl
      __builtin_amdgcn_global_load_lds(
          (gas_ptr)(csrc + grow*64 + lcg*4),
          (las_ptr)(ldst + (wvu*16 + k*4)*64), 16, 0, 0);
    }
  };

  // ---- prologue: stage chunks 0 and 1
  stage(wmb,         &xs[0][0]);
  stage(wmb + 64*L_, &xs[1][0]);
  asm volatile("s_waitcnt vmcnt(4)" ::: "memory");   // chunk0 done, chunk1 in flight
  __builtin_amdgcn_s_barrier();

  #pragma unroll
  for (int ch = 0; ch < 8; ++ch) {
    float* xb = &xs[ch & 3][0];                       // compile-time constant

    // ---- issue async staging of chunk ch+2 (window = 2 full chunks)
    if (ch < 6)
      stage(wmb + (ch+2) * (64*L_), &xs[(ch+2) & 3][0]);

    // ---- score: lane owns row w=lane, wave owns j-pair
    float a10 = 0.f, a11 = 0.f, a20 = 0.f, a21 = 0.f;
    #pragma unroll
    for (int c = 0; c < 16; ++c) {
      const int col = c ^ wm15;
      float4 x = *(const float4*)&xb[lane*64 + col*4];
      float4 xq;
      xq.x = x.x*x.x; xq.y = x.y*x.y; xq.z = x.z*x.z; xq.w = x.w*x.w;
      float4 wc0 = *(const float4*)(wcg + (j0  )*L_ + c*4);   // scalar (j0 uniform)
      float4 wc1 = *(const float4*)(wcg + (j0+1)*L_ + c*4);
      float4 w10 = *(const float4*)(w1g + (j0  )*L_ + c*4);
      float4 w11 = *(const float4*)(w1g + (j0+1)*L_ + c*4);
      a10 = fmaf(wc0.x, x.x, a10); a10 = fmaf(wc0.y, x.y, a10);
      a10 = fmaf(wc0.z, x.z, a10); a10 = fmaf(wc0.w, x.w, a10);
      a11 = fmaf(wc1.x, x.x, a11); a11 = fmaf(wc1.y, x.y, a11);
      a11 = fmaf(wc1.z, x.z, a11); a11 = fmaf(wc1.w, x.w, a11);
      a20 = fmaf(w10.x, xq.x, a20); a20 = fmaf(w10.y, xq.y, a20);
      a20 = fmaf(w10.z, xq.z, a20); a20 = fmaf(w10.w, xq.w, a20);
      a21 = fmaf(w11.x, xq.x, a21); a21 = fmaf(w11.y, xq.y, a21);
      a21 = fmaf(w11.z, xq.z, a21); a21 = fmaf(w11.w, xq.w, a21);
    }
    float s0v = Ag[j0]   + a10 + a20;   // wcg already holds -2*w1*c
    float s1v = Ag[j0+1] + a11 + a21;

    if (ch == 0) {   // stabilizer: pure wave-reduce (scores >= 0, chunk-0 min safe)
      float mn0 = s0v, mn1 = s1v;
      #pragma unroll
      for (int off = 1; off < 64; off <<= 1) {
        mn0 = fminf(mn0, __shfl_xor(mn0, off));
        mn1 = fminf(mn1, __shfl_xor(mn1, off));
      }
      m0v[0] = mn0; m0v[1] = mn1;
    }

    float e0 = __expf(m0v[0] - s0v);
    float e1 = __expf(m0v[1] - s1v);
    esum[0] += e0; msum[0] = fmaf(e0, s0v, msum[0]);
    esum[1] += e1; msum[1] = fmaf(e1, s1v, msum[1]);
    es[(j0  )*64 + lane] = e0;
    es[(j0+1)*64 + lane] = e1;

    // es publish: lgkmcnt only — both in-flight prefetch chunks untouched.
    asm volatile("s_waitcnt lgkmcnt(0)" ::: "memory");
    __builtin_amdgcn_s_barrier();

    // ---- accumulate partial best: thread (lq, wsl) owns 16B slot lq, rows wsl*4..+3
    float4 x4[4];
    #pragma unroll
    for (int t = 0; t < 4; ++t) {
      const int w2 = wsl*4 + t;
      const int col = lq ^ (w2 & 15);
      x4[t] = *(const float4*)&xb[w2*64 + col*4];
    }
    #pragma unroll
    for (int j = 0; j < J_; ++j) {
      float4 e4 = *(const float4*)&es[j*64 + wsl*4];   // 16-lane broadcast
      accb[j][0] = fmaf(e4.x, x4[0].x, accb[j][0]);
      accb[j][1] = fmaf(e4.x, x4[0].y, accb[j][1]);
      accb[j][2] = fmaf(e4.x, x4[0].z, accb[j][2]);
      accb[j][3] = fmaf(e4.x, x4[0].w, accb[j][3]);
      accb[j][0] = fmaf(e4.y, x4[1].x, accb[j][0]);
      accb[j][1] = fmaf(e4.y, x4[1].y, accb[j][1]);
      accb[j][2] = fmaf(e4.y, x4[1].z, accb[j][2]);
      accb[j][3] = fmaf(e4.y, x4[1].w, accb[j][3]);
      accb[j][0] = fmaf(e4.z, x4[2].x, accb[j][0]);
      accb[j][1] = fmaf(e4.z, x4[2].y, accb[j][1]);
      accb[j][2] = fmaf(e4.z, x4[2].z, accb[j][2]);
      accb[j][3] = fmaf(e4.z, x4[2].w, accb[j][3]);
      accb[j][0] = fmaf(e4.w, x4[3].x, accb[j][0]);
      accb[j][1] = fmaf(e4.w, x4[3].y, accb[j][1]);
      accb[j][2] = fmaf(e4.w, x4[3].z, accb[j][2]);
      accb[j][3] = fmaf(e4.w, x4[3].w, accb[j][3]);
    }

    // end-of-chunk: retire ONLY the chunk needed next iteration.
    if (ch <= 5)
      asm volatile("s_waitcnt vmcnt(4) lgkmcnt(0)" ::: "memory");
    else if (ch == 6)
      asm volatile("s_waitcnt vmcnt(0) lgkmcnt(0)" ::: "memory");
    else
      asm volatile("s_waitcnt lgkmcnt(0)" ::: "memory");
    __builtin_amdgcn_s_barrier();
  }

  // ---- stats: wave-local reduce, lane 0 writes both j's
  #pragma unroll
  for (int u = 0; u < 2; ++u) {
    float e = esum[u], m = msum[u];
    #pragma unroll
    for (int off = 1; off < 64; off <<= 1) {
      e += __shfl_xor(e, off);
      m += __shfl_xor(m, off);
    }
    if (lane == 0) {
      float* st = stats + (((size_t)h*B_ + b)*J_ + (j0+u))*4;
      st[0] = m0v[u]; st[1] = e; st[2] = m;
    }
  }

  // ---- reduce accb over the 16 w-slots (reuse xs; final loop barrier protects)
  float* xsf = &xs[0][0];
  #pragma unroll
  for (int j = 0; j < J_; ++j)
    *(float4*)&xsf[((wsl*J_ + j)*16 + lq)*4] = *(float4*)accb[j];
  __syncthreads();
  if (tid < J_*16) {
    int j = tid >> 4, q = tid & 15;
    float4 sum = make_float4(0.f, 0.f, 0.f, 0.f);
    #pragma unroll
    for (int s2i = 0; s2i < 16; ++s2i) {
      float4 p = *(const float4*)&xsf[((s2i*J_ + j)*16 + q)*4];
      sum.x += p.x; sum.y += p.y; sum.z += p.z; sum.w += p.w;
    }
    *(float4*)&bpart[(((size_t)h*J_ + j)*B_ + b)*L_ + q*4] = sum;
  }
}

// ---------------------------------------------------------------- K2b: combine halves
__global__ __launch_bounds__(128) void k2b_combine(const float* __restrict__ bpart,
    const float* __restrict__ stats, float* __restrict__ best, float* __restrict__ conf)
{
  __shared__ float mred[J_];
  const int b = blockIdx.x, tid = threadIdx.x;
  const int j = tid >> 4, q = tid & 15;
  const float* st0 = stats + ((size_t)b*J_ + j)*4;
  const float* st1 = stats + (((size_t)B_ + b)*J_ + j)*4;
  float m0a = st0[0], E0 = st0[1], M0 = st0[2];
  float m0b = st1[0], E1 = st1[1], M1 = st1[2];
  float M = fminf(m0a, m0b);
  float s0 = __expf(M - m0a), s1 = __expf(M - m0b);
  float E = s0*E0 + s1*E1;
  float inv = 1.f / E;
  float4 p0 = *(const float4*)&bpart[((size_t)j*B_ + b)*L_ + q*4];
  float4 p1 = *(const float4*)&bpart[(((size_t)J_ + j)*B_ + b)*L_ + q*4];
  float4 o;
  o.x = (s0*p0.x + s1*p1.x) * inv;
  o.y = (s0*p0.y + s1*p1.y) * inv;
  o.z = (s0*p0.z + s1*p1.z) * inv;
  o.w = (s0*p0.w + s1*p1.w) * inv;
  *(float4*)&best[((size_t)j*B_ + b)*L_ + q*4] = o;
  if (q == 0) mred[j] = (s0*M0 + s1*M1) * inv;
  __syncthreads();
  if (tid == 0) {
    float mq = 0.f;
    #pragma unroll
    for (int jj = 0; jj < J_; ++jj) mq += mred[jj];
    conf[b] = __expf(-mq);
  }
}

// ---------------------------------------------------------------- K3: slot path, 4-way b ILP, no max-stabilizer
__global__ __launch_bounds__(256) void k3_slot(const float* __restrict__ slot_w,
    const float* __restrict__ slot_b, const float* __restrict__ best,
    float* __restrict__ partial)
{
  const int bx = blockIdx.y;            // (j, lgroup)
  const int j = bx >> 3, lg = bx & 7;
  const int bc = blockIdx.x;            // b-chunk fast dim -> L2 reuse
  const int tid = threadIdx.x;
  const int wv = tid >> 6, lane = tid & 63;
  const int l2 = lane >> 5, i = lane & 31;
  const int l = lg*8 + wv*2 + l2;
  const int r = l*I_ + i;

  const float* swr = slot_w + ((size_t)j*(L_*I_) + r) * L_;
  float sw[L_];
  #pragma unroll
  for (int c = 0; c < 16; ++c) {
    float4 t = ((const float4*)swr)[c];
    sw[c*4+0] = t.x; sw[c*4+1] = t.y; sw[c*4+2] = t.z; sw[c*4+3] = t.w;
  }
  const float sb = slot_b[j*(L_*I_) + r];
  const float* bestj = best + (size_t)j * B_ * L_;
  float* pout = partial + (size_t)bx * (B_*I_);
  const int lidx = lg*8 + wv*2;

  for (int bi = 0; bi < 32; bi += 4) {
    const int b0 = bc*32 + bi;
    const float* bw[4];
    #pragma unroll
    for (int u = 0; u < 4; ++u) bw[u] = bestj + (size_t)(b0+u) * L_;  // uniform -> s_load
    float pa[4], pb[4];
    #pragma unroll
    for (int u = 0; u < 4; ++u) { pa[u] = sb; pb[u] = 0.f; }
    #pragma unroll
    for (int c = 0; c < L_; c += 2) {
      #pragma unroll
      for (int u = 0; u < 4; ++u) {
        pa[u] = fmaf(bw[u][c+0], sw[c+0], pa[u]);
        pb[u] = fmaf(bw[u][c+1], sw[c+1], pb[u]);
      }
    }
    float e[4], sm[4];
    #pragma unroll
    for (int u = 0; u < 4; ++u) { e[u] = __expf(pa[u] + pb[u]); sm[u] = e[u]; }
    #pragma unroll
    for (int mask = 16; mask; mask >>= 1)
      #pragma unroll
      for (int u = 0; u < 4; ++u) sm[u] += __shfl_xor(sm[u], mask);
    float cv[4];
    #pragma unroll
    for (int u = 0; u < 4; ++u) {
      float bv = l2 ? bw[u][lidx+1] : bw[u][lidx];
      cv[u] = (e[u] / sm[u]) * bv;
    }
    #pragma unroll
    for (int u = 0; u < 4; ++u) cv[u] += __shfl_xor(cv[u], 32);
    if (l2 == 0) {
      #pragma unroll
      for (int u = 0; u < 4; ++u)
        pout[(size_t)(b0+u)*I_ + i] = cv[u];
    }
  }
}

// ---------------------------------------------------------------- K4: reduce + body + head + confidence
__global__ __launch_bounds__(128) void k4_head(const float* __restrict__ partial,
    const float* __restrict__ best, const float* __restrict__ gammas,
    const float* __restrict__ body_w, const float* __restrict__ body_b,
    const float* __restrict__ head_w, const float* __restrict__ head_b,
    const float* __restrict__ conf, float* __restrict__ out)
{
  __shared__ float gavg[J_];
  __shared__ float cvred[4][I_];
  __shared__ float cvf[I_];
  const int b = blockIdx.x, tid = threadIdx.x;
  const int i = tid & 31, q = tid >> 5;
  if (tid < J_) {
    float gsum = 0.f;
    for (int l = 0; l < L_; ++l) {
      float g = gammas[tid*L_ + l];
      gsum += fminf(fmaxf(g, 0.f), 1.f);
    }
    gavg[tid] = gsum * (1.f / L_);
  }
  __syncthreads();

  float acc = 0.f;
  for (int s = q; s < 64; s += 4)
    acc += partial[((size_t)s*B_ + b)*I_ + i];

  #pragma unroll
  for (int u = 0; u < 2; ++u) {
    const int j = q + u*4;
    const float* bwv  = best + ((size_t)j*B_ + b)*L_;
    const float* wrow = body_w + (size_t)(j*I_ + i)*L_;
    float d0 = body_b[j*I_ + i], d1 = 0.f, d2 = 0.f, d3 = 0.f;
    #pragma unroll
    for (int c = 0; c < L_; c += 4) {
      d0 = fmaf(bwv[c+0], wrow[c+0], d0);
      d1 = fmaf(bwv[c+1], wrow[c+1], d1);
      d2 = fmaf(bwv[c+2], wrow[c+2], d2);
      d3 = fmaf(bwv[c+3], wrow[c+3], d3);
    }
    acc = fmaf(gavg[j], (d0 + d1) + (d2 + d3), acc);
  }
  cvred[q][i] = acc;
  __syncthreads();
  if (tid < I_)
    cvf[i] = cvred[0][i] + cvred[1][i] + cvred[2][i] + cvred[3][i];
  __syncthreads();
  float oacc = head_b[tid];
  #pragma unroll
  for (int i2 = 0; i2 < I_; ++i2) oacc = fmaf(cvf[i2], head_w[tid*I_ + i2], oacc);
  out[(size_t)b*O_ + tid] = conf[b] * oacc;
}

extern "C" void kernel_launch(void* const* d_in, const int* in_sizes, int n_in,
                              void* d_out, int out_size, void* d_ws, size_t ws_size,
                              hipStream_t stream) {
  const float* wm        = (const float*)d_in[0];
  const float* constants = (const float*)d_in[1];
  const float* gammas    = (const float*)d_in[2];
  const float* body_w    = (const float*)d_in[3];
  const float* body_b    = (const float*)d_in[4];
  const float* slot_w    = (const float*)d_in[5];
  const float* slot_b    = (const float*)d_in[6];
  const float* head_w    = (const float*)d_in[7];
  const float* head_b    = (const float*)d_in[8];
  float* out = (float*)d_out;

  float* ws      = (float*)d_ws;
  float* wcg     = ws;
  float* w1g     = wcg + J_*L_;
  float* Ag      = w1g + J_*L_;
  float* best    = Ag + 16;
  float* conf    = best + (size_t)J_*B_*L_;
  float* partial = conf + B_;
  float* bpart   = partial + (size_t)64*B_*I_;
  float* stats   = bpart + (size_t)2*J_*B_*L_;

  hipLaunchKernelGGL(k0_prep, dim3(1), dim3(64), 0, stream,
                     constants, gammas, wcg, w1g, Ag);
  hipLaunchKernelGGL(k12_fused, dim3(B_, 2), dim3(256), 0, stream,
                     wm, wcg, w1g, Ag, bpart, stats);
  hipLaunchKernelGGL(k2b_combine, dim3(B_), dim3(128), 0, stream,
                     bpart, stats, best, conf);
  hipLaunchKernelGGL(k3_slot, dim3(16, 64), dim3(256), 0, stream,
                     slot_w, slot_b, best, partial);
  hipLaunchKernelGGL(k4_head, dim3(B_), dim3(128), 0, stream,
                     partial, best, gammas, body_w, body_b, head_w, head_b, conf, out);
}

// Round 6
// 322.264 us; speedup vs baseline: 1.0464x; 1.0464x over previous
//
#include <hip/hip_runtime.h>
#include <cstdint>
#include <cstddef>

#define B_ 512
#define W_ 1024
#define L_ 64
#define J_ 8
#define I_ 32
#define O_ 128

// ws layout (floats):
// wcg   : [J][L]        = 512   (holds -2*(1-g)*c)
// w1g   : [J][L]        = 512
// Ag    : [J] (+pad)    = 16
// best  : [J][B][L]     = 262144
// conf  : [B]           = 512
// partial:[64][B][I]    = 1048576
// bpart : [2][J][B][L]  = 524288
// stats : [2][B][J][4]  = 32768

typedef const __attribute__((address_space(1))) void* gas_ptr;
typedef __attribute__((address_space(3))) void* las_ptr;

// ---------------------------------------------------------------- K0
__global__ __launch_bounds__(64) void k0_prep(const float* __restrict__ constants,
    const float* __restrict__ gammas, float* __restrict__ wcg,
    float* __restrict__ w1g, float* __restrict__ Ag)
{
  const int l = threadIdx.x;
  #pragma unroll
  for (int j = 0; j < J_; ++j) {
    float g = gammas[j*L_ + l];
    g = fminf(fmaxf(g, 0.f), 1.f);
    float c = constants[j*L_ + l];
    float w1 = 1.f - g;
    w1g[j*L_ + l] = w1;
    wcg[j*L_ + l] = -2.f * w1 * c;   // fold the -2 of the cross term here
  }
  if (l < J_) {
    float a = 0.f;
    for (int c = 0; c < L_; ++c) {
      float g = gammas[l*L_ + c];
      g = fminf(fmaxf(g, 0.f), 1.f);
      float cc = constants[l*L_ + c];
      a += (1.f - g) * cc * cc;
    }
    Ag[l] = a;
  }
}

// ---------------------------------------------------------------- K12 v6:
// WAVE-INDEPENDENT j-pair pipeline. Each wave owns j-pair {2wv,2wv+1}
// END-TO-END: score (lane=row, all 64 rows) -> e (wave-local es scratch,
// published by lgkmcnt(0) only — NO barrier) -> accum of best[j-pair]
// with lanes remapped to (colgroup cg=lane&15, row-quarter rs=lane>>4).
// The cross-wave e-exchange of v2 (and its mid-chunk barrier + final
// cross-slot LDS reduction) is GONE. One barrier per chunk, for buffer
// publish only. accb shrinks 32->8 regs -> VGPR ~90 -> 4 blocks/CU.
//
// Depth-1 staging (v2's, the proven one): stage(ch+1) at top of chunk,
// vmcnt(0) at end — window = full chunk compute (score+accum, no
// barrier in between). r2/r5 showed depth-2 costs registers it can't pay.
//
// Swizzle invariant (from the DMA): LDS[row][g] = global[row][g^(row&15)]
//   score reads global group c     -> LDS group c ^ (lane&15)
//   accum reads global group cg    -> LDS group cg ^ (w&15)
// es scratch: es[wave][w][0..1] = (e0,e1); accum reads float4 (w,w+1
// pair, 16-lane broadcast, same-address = conflict-free).
__global__ __launch_bounds__(256, 4) void k12_fused(const float* __restrict__ wm,
    const float* __restrict__ wcg, const float* __restrict__ w1g,
    const float* __restrict__ Ag, float* __restrict__ bpart, float* __restrict__ stats)
{
  __shared__ __align__(16) float xs[2][64 * 64];   // 32768 B
  __shared__ __align__(16) float es[4][64 * 2];    // 2048 B (per-wave scratch)

  const int tid = threadIdx.x;
  const int b = blockIdx.x, h = blockIdx.y;
  const int lane = tid & 63;
  const int wvu = __builtin_amdgcn_readfirstlane(tid >> 6);  // wave id (uniform)
  const int j0  = wvu * 2;                                   // this wave's j-pair
  const int wm15 = lane & 15;                                // score swizzle key (row&15)
  const int cg = lane & 15, rs = lane >> 4;                  // accum mapping
  const int rl = lane >> 4, pcg = lane & 15;                 // staging decomposition

  const float* wmb = wm + (size_t)b * (W_*L_) + (size_t)h * (512*L_);

  float acc0[4] = {0.f, 0.f, 0.f, 0.f};   // best[j0][cg*4..+3]
  float acc1[4] = {0.f, 0.f, 0.f, 0.f};   // best[j0+1][cg*4..+3]
  float esum[2] = {0.f, 0.f}, msum[2] = {0.f, 0.f}, m0v[2];

  auto stage = [&](const float* csrc, float* ldst) {
    #pragma unroll
    for (int k = 0; k < 4; ++k) {
      const int grow = wvu*16 + k*4 + rl;
      const int lcg  = pcg ^ (k*4 + rl);         // (grow&15) == k*4+rl
      __builtin_amdgcn_global_load_lds(
          (gas_ptr)(csrc + grow*64 + lcg*4),
          (las_ptr)(ldst + (wvu*16 + k*4)*64), 16, 0, 0);
    }
  };

  // ---- prologue: stage chunk 0 (one-time full drain; ~1 DMA latency)
  stage(wmb, &xs[0][0]);
  asm volatile("s_waitcnt vmcnt(0)" ::: "memory");
  __builtin_amdgcn_s_barrier();

  for (int ch = 0; ch < 8; ++ch) {
    float* xb = &xs[ch & 1][0];

    // ---- issue staging of chunk ch+1 (drained at END of this chunk:
    //      window = the whole score+accum compute, no barrier between)
    if (ch < 7)
      stage(wmb + (ch+1) * (64*L_), &xs[(ch+1) & 1][0]);

    // ---- score: lane owns row w=lane, wave owns j-pair
    float a10 = 0.f, a11 = 0.f, a20 = 0.f, a21 = 0.f;
    #pragma unroll
    for (int c = 0; c < 16; ++c) {
      const int col = c ^ wm15;
      float4 x = *(const float4*)&xb[lane*64 + col*4];
      float4 xq;
      xq.x = x.x*x.x; xq.y = x.y*x.y; xq.z = x.z*x.z; xq.w = x.w*x.w;
      float4 wc0 = *(const float4*)(wcg + (j0  )*L_ + c*4);   // scalar (j0 uniform)
      float4 wc1 = *(const float4*)(wcg + (j0+1)*L_ + c*4);
      float4 w10 = *(const float4*)(w1g + (j0  )*L_ + c*4);
      float4 w11 = *(const float4*)(w1g + (j0+1)*L_ + c*4);
      a10 = fmaf(wc0.x, x.x, a10); a10 = fmaf(wc0.y, x.y, a10);
      a10 = fmaf(wc0.z, x.z, a10); a10 = fmaf(wc0.w, x.w, a10);
      a11 = fmaf(wc1.x, x.x, a11); a11 = fmaf(wc1.y, x.y, a11);
      a11 = fmaf(wc1.z, x.z, a11); a11 = fmaf(wc1.w, x.w, a11);
      a20 = fmaf(w10.x, xq.x, a20); a20 = fmaf(w10.y, xq.y, a20);
      a20 = fmaf(w10.z, xq.z, a20); a20 = fmaf(w10.w, xq.w, a20);
      a21 = fmaf(w11.x, xq.x, a21); a21 = fmaf(w11.y, xq.y, a21);
      a21 = fmaf(w11.z, xq.z, a21); a21 = fmaf(w11.w, xq.w, a21);
    }
    float s0v = Ag[j0]   + a10 + a20;   // wcg already holds -2*w1*c
    float s1v = Ag[j0+1] + a11 + a21;

    if (ch == 0) {   // stabilizer: pure wave-reduce (scores >= 0, chunk-0 min safe)
      float mn0 = s0v, mn1 = s1v;
      #pragma unroll
      for (int off = 1; off < 64; off <<= 1) {
        mn0 = fminf(mn0, __shfl_xor(mn0, off));
        mn1 = fminf(mn1, __shfl_xor(mn1, off));
      }
      m0v[0] = mn0; m0v[1] = mn1;
    }

    float e0 = __expf(m0v[0] - s0v);
    float e1 = __expf(m0v[1] - s1v);
    esum[0] += e0; msum[0] = fmaf(e0, s0v, msum[0]);
    esum[1] += e1; msum[1] = fmaf(e1, s1v, msum[1]);
    // wave-local publish: lane=row w writes (e0,e1) pair
    *(float2*)&es[wvu][lane*2] = make_float2(e0, e1);

    // wave-local wait ONLY — no barrier. Retires my es write AND my
    // score ds_reads; other waves proceed independently.
    asm volatile("s_waitcnt lgkmcnt(0)" ::: "memory");

    // ---- accum: lane (cg, rs) accumulates best[j0/j0+1][cg*4..+3]
    //      over rows w = rs*16 .. rs*16+15 of this chunk.
    #pragma unroll
    for (int it = 0; it < 16; it += 2) {
      const int w0 = rs*16 + it;
      float4 e4 = *(const float4*)&es[wvu][w0*2];     // e0,e1 of w0 and w0+1 (broadcast)
      float4 xA = *(const float4*)&xb[w0*64     + (cg ^ ( w0    & 15))*4];
      float4 xB = *(const float4*)&xb[(w0+1)*64 + (cg ^ ((w0+1) & 15))*4];
      acc0[0] = fmaf(e4.x, xA.x, acc0[0]); acc0[1] = fmaf(e4.x, xA.y, acc0[1]);
      acc0[2] = fmaf(e4.x, xA.z, acc0[2]); acc0[3] = fmaf(e4.x, xA.w, acc0[3]);
      acc1[0] = fmaf(e4.y, xA.x, acc1[0]); acc1[1] = fmaf(e4.y, xA.y, acc1[1]);
      acc1[2] = fmaf(e4.y, xA.z, acc1[2]); acc1[3] = fmaf(e4.y, xA.w, acc1[3]);
      acc0[0] = fmaf(e4.z, xB.x, acc0[0]); acc0[1] = fmaf(e4.z, xB.y, acc0[1]);
      acc0[2] = fmaf(e4.z, xB.z, acc0[2]); acc0[3] = fmaf(e4.z, xB.w, acc0[3]);
      acc1[0] = fmaf(e4.w, xB.x, acc1[0]); acc1[1] = fmaf(e4.w, xB.y, acc1[1]);
      acc1[2] = fmaf(e4.w, xB.z, acc1[2]); acc1[3] = fmaf(e4.w, xB.w, acc1[3]);
    }

    // end-of-chunk: my LDS reads retired (buffer + es recyclable),
    // next chunk's DMA complete, then publish across waves.
    if (ch < 7) {
      asm volatile("s_waitcnt vmcnt(0) lgkmcnt(0)" ::: "memory");
      __builtin_amdgcn_s_barrier();
    }
  }

  // ---- stats: wave-local reduce, lane 0 writes both j's
  #pragma unroll
  for (int u = 0; u < 2; ++u) {
    float e = esum[u], m = msum[u];
    #pragma unroll
    for (int off = 1; off < 64; off <<= 1) {
      e += __shfl_xor(e, off);
      m += __shfl_xor(m, off);
    }
    if (lane == 0) {
      float* st = stats + (((size_t)h*B_ + b)*J_ + (j0+u))*4;
      st[0] = m0v[u]; st[1] = e; st[2] = m;
    }
  }

  // ---- epilogue: fold the 4 row-quarters (rs) — pure shuffle, no LDS
  #pragma unroll
  for (int q = 0; q < 4; ++q) {
    acc0[q] += __shfl_xor(acc0[q], 16);
    acc0[q] += __shfl_xor(acc0[q], 32);
    acc1[q] += __shfl_xor(acc1[q], 16);
    acc1[q] += __shfl_xor(acc1[q], 32);
  }
  if (lane < 16) {   // lane == cg
    float* bp0 = &bpart[(((size_t)h*J_ + j0    )*B_ + b)*L_ + cg*4];
    float* bp1 = &bpart[(((size_t)h*J_ + j0 + 1)*B_ + b)*L_ + cg*4];
    *(float4*)bp0 = make_float4(acc0[0], acc0[1], acc0[2], acc0[3]);
    *(float4*)bp1 = make_float4(acc1[0], acc1[1], acc1[2], acc1[3]);
  }
}

// ---------------------------------------------------------------- K2b: combine halves
__global__ __launch_bounds__(128) void k2b_combine(const float* __restrict__ bpart,
    const float* __restrict__ stats, float* __restrict__ best, float* __restrict__ conf)
{
  __shared__ float mred[J_];
  const int b = blockIdx.x, tid = threadIdx.x;
  const int j = tid >> 4, q = tid & 15;
  const float* st0 = stats + ((size_t)b*J_ + j)*4;
  const float* st1 = stats + (((size_t)B_ + b)*J_ + j)*4;
  float m0a = st0[0], E0 = st0[1], M0 = st0[2];
  float m0b = st1[0], E1 = st1[1], M1 = st1[2];
  float M = fminf(m0a, m0b);
  float s0 = __expf(M - m0a), s1 = __expf(M - m0b);
  float E = s0*E0 + s1*E1;
  float inv = 1.f / E;
  float4 p0 = *(const float4*)&bpart[((size_t)j*B_ + b)*L_ + q*4];
  float4 p1 = *(const float4*)&bpart[(((size_t)J_ + j)*B_ + b)*L_ + q*4];
  float4 o;
  o.x = (s0*p0.x + s1*p1.x) * inv;
  o.y = (s0*p0.y + s1*p1.y) * inv;
  o.z = (s0*p0.z + s1*p1.z) * inv;
  o.w = (s0*p0.w + s1*p1.w) * inv;
  *(float4*)&best[((size_t)j*B_ + b)*L_ + q*4] = o;
  if (q == 0) mred[j] = (s0*M0 + s1*M1) * inv;
  __syncthreads();
  if (tid == 0) {
    float mq = 0.f;
    #pragma unroll
    for (int jj = 0; jj < J_; ++jj) mq += mred[jj];
    conf[b] = __expf(-mq);
  }
}

// ---------------------------------------------------------------- K3: slot path, 4-way b ILP, no max-stabilizer
__global__ __launch_bounds__(256) void k3_slot(const float* __restrict__ slot_w,
    const float* __restrict__ slot_b, const float* __restrict__ best,
    float* __restrict__ partial)
{
  const int bx = blockIdx.y;            // (j, lgroup)
  const int j = bx >> 3, lg = bx & 7;
  const int bc = blockIdx.x;            // b-chunk fast dim -> L2 reuse
  const int tid = threadIdx.x;
  const int wv = tid >> 6, lane = tid & 63;
  const int l2 = lane >> 5, i = lane & 31;
  const int l = lg*8 + wv*2 + l2;
  const int r = l*I_ + i;

  const float* swr = slot_w + ((size_t)j*(L_*I_) + r) * L_;
  float sw[L_];
  #pragma unroll
  for (int c = 0; c < 16; ++c) {
    float4 t = ((const float4*)swr)[c];
    sw[c*4+0] = t.x; sw[c*4+1] = t.y; sw[c*4+2] = t.z; sw[c*4+3] = t.w;
  }
  const float sb = slot_b[j*(L_*I_) + r];
  const float* bestj = best + (size_t)j * B_ * L_;
  float* pout = partial + (size_t)bx * (B_*I_);
  const int lidx = lg*8 + wv*2;

  for (int bi = 0; bi < 32; bi += 4) {
    const int b0 = bc*32 + bi;
    const float* bw[4];
    #pragma unroll
    for (int u = 0; u < 4; ++u) bw[u] = bestj + (size_t)(b0+u) * L_;  // uniform -> s_load
    float pa[4], pb[4];
    #pragma unroll
    for (int u = 0; u < 4; ++u) { pa[u] = sb; pb[u] = 0.f; }
    #pragma unroll
    for (int c = 0; c < L_; c += 2) {
      #pragma unroll
      for (int u = 0; u < 4; ++u) {
        pa[u] = fmaf(bw[u][c+0], sw[c+0], pa[u]);
        pb[u] = fmaf(bw[u][c+1], sw[c+1], pb[u]);
      }
    }
    float e[4], sm[4];
    #pragma unroll
    for (int u = 0; u < 4; ++u) { e[u] = __expf(pa[u] + pb[u]); sm[u] = e[u]; }
    #pragma unroll
    for (int mask = 16; mask; mask >>= 1)
      #pragma unroll
      for (int u = 0; u < 4; ++u) sm[u] += __shfl_xor(sm[u], mask);
    float cv[4];
    #pragma unroll
    for (int u = 0; u < 4; ++u) {
      float bv = l2 ? bw[u][lidx+1] : bw[u][lidx];
      cv[u] = (e[u] / sm[u]) * bv;
    }
    #pragma unroll
    for (int u = 0; u < 4; ++u) cv[u] += __shfl_xor(cv[u], 32);
    if (l2 == 0) {
      #pragma unroll
      for (int u = 0; u < 4; ++u)
        pout[(size_t)(b0+u)*I_ + i] = cv[u];
    }
  }
}

// ---------------------------------------------------------------- K4: reduce + body + head + confidence
__global__ __launch_bounds__(128) void k4_head(const float* __restrict__ partial,
    const float* __restrict__ best, const float* __restrict__ gammas,
    const float* __restrict__ body_w, const float* __restrict__ body_b,
    const float* __restrict__ head_w, const float* __restrict__ head_b,
    const float* __restrict__ conf, float* __restrict__ out)
{
  __shared__ float gavg[J_];
  __shared__ float cvred[4][I_];
  __shared__ float cvf[I_];
  const int b = blockIdx.x, tid = threadIdx.x;
  const int i = tid & 31, q = tid >> 5;
  if (tid < J_) {
    float gsum = 0.f;
    for (int l = 0; l < L_; ++l) {
      float g = gammas[tid*L_ + l];
      gsum += fminf(fmaxf(g, 0.f), 1.f);
    }
    gavg[tid] = gsum * (1.f / L_);
  }
  __syncthreads();

  float acc = 0.f;
  for (int s = q; s < 64; s += 4)
    acc += partial[((size_t)s*B_ + b)*I_ + i];

  #pragma unroll
  for (int u = 0; u < 2; ++u) {
    const int j = q + u*4;
    const float* bwv  = best + ((size_t)j*B_ + b)*L_;
    const float* wrow = body_w + (size_t)(j*I_ + i)*L_;
    float d0 = body_b[j*I_ + i], d1 = 0.f, d2 = 0.f, d3 = 0.f;
    #pragma unroll
    for (int c = 0; c < L_; c += 4) {
      d0 = fmaf(bwv[c+0], wrow[c+0], d0);
      d1 = fmaf(bwv[c+1], wrow[c+1], d1);
      d2 = fmaf(bwv[c+2], wrow[c+2], d2);
      d3 = fmaf(bwv[c+3], wrow[c+3], d3);
    }
    acc = fmaf(gavg[j], (d0 + d1) + (d2 + d3), acc);
  }
  cvred[q][i] = acc;
  __syncthreads();
  if (tid < I_)
    cvf[i] = cvred[0][i] + cvred[1][i] + cvred[2][i] + cvred[3][i];
  __syncthreads();
  float oacc = head_b[tid];
  #pragma unroll
  for (int i2 = 0; i2 < I_; ++i2) oacc = fmaf(cvf[i2], head_w[tid*I_ + i2], oacc);
  out[(size_t)b*O_ + tid] = conf[b] * oacc;
}

extern "C" void kernel_launch(void* const* d_in, const int* in_sizes, int n_in,
                              void* d_out, int out_size, void* d_ws, size_t ws_size,
                              hipStream_t stream) {
  const float* wm        = (const float*)d_in[0];
  const float* constants = (const float*)d_in[1];
  const float* gammas    = (const float*)d_in[2];
  const float* body_w    = (const float*)d_in[3];
  const float* body_b    = (const float*)d_in[4];
  const float* slot_w    = (const float*)d_in[5];
  const float* slot_b    = (const float*)d_in[6];
  const float* head_w    = (const float*)d_in[7];
  const float* head_b    = (const float*)d_in[8];
  float* out = (float*)d_out;

  float* ws      = (float*)d_ws;
  float* wcg     = ws;
  float* w1g     = wcg + J_*L_;
  float* Ag      = w1g + J_*L_;
  float* best    = Ag + 16;
  float* conf    = best + (size_t)J_*B_*L_;
  float* partial = conf + B_;
  float* bpart   = partial + (size_t)64*B_*I_;
  float* stats   = bpart + (size_t)2*J_*B_*L_;

  hipLaunchKernelGGL(k0_prep, dim3(1), dim3(64), 0, stream,
                     constants, gammas, wcg, w1g, Ag);
  hipLaunchKernelGGL(k12_fused, dim3(B_, 2), dim3(256), 0, stream,
                     wm, wcg, w1g, Ag, bpart, stats);
  hipLaunchKernelGGL(k2b_combine, dim3(B_), dim3(128), 0, stream,
                     bpart, stats, best, conf);
  hipLaunchKernelGGL(k3_slot, dim3(16, 64), dim3(256), 0, stream,
                     slot_w, slot_b, best, partial);
  hipLaunchKernelGGL(k4_head, dim3(B_), dim3(128), 0, stream,
                     partial, best, gammas, body_w, body_b, head_w, head_b, conf, out);
}

// Round 7
// 282.907 us; speedup vs baseline: 1.1920x; 1.1391x over previous
//
#include <hip/hip_runtime.h>
#include <cstdint>
#include <cstddef>

#define B_ 512
#define W_ 1024
#define L_ 64
#define J_ 8
#define I_ 32
#define O_ 128

// ws layout (floats):
// wcg   : [J][L]        = 512   (holds -2*(1-g)*c)
// w1g   : [J][L]        = 512
// Ag    : [J] (+pad)    = 16
// best  : [J][B][L]     = 262144
// conf  : [B]           = 512
// partial:[64][B][I]    = 1048576
// bpart : [2][J][B][L]  = 524288
// stats : [2][B][J][4]  = 32768

typedef const __attribute__((address_space(1))) void* gas_ptr;
typedef __attribute__((address_space(3))) void* las_ptr;

// ---------------------------------------------------------------- K0
__global__ __launch_bounds__(64) void k0_prep(const float* __restrict__ constants,
    const float* __restrict__ gammas, float* __restrict__ wcg,
    float* __restrict__ w1g, float* __restrict__ Ag)
{
  const int l = threadIdx.x;
  #pragma unroll
  for (int j = 0; j < J_; ++j) {
    float g = gammas[j*L_ + l];
    g = fminf(fmaxf(g, 0.f), 1.f);
    float c = constants[j*L_ + l];
    float w1 = 1.f - g;
    w1g[j*L_ + l] = w1;
    wcg[j*L_ + l] = -2.f * w1 * c;   // fold the -2 of the cross term here
  }
  if (l < J_) {
    float a = 0.f;
    for (int c = 0; c < L_; ++c) {
      float g = gammas[l*L_ + c];
      g = fminf(fmaxf(g, 0.f), 1.f);
      float cc = constants[l*L_ + c];
      a += (1.f - g) * cc * cc;
    }
    Ag[l] = a;
  }
}

// ---------------------------------------------------------------- K12 v6b:
// WAVE-INDEPENDENT j-pair pipeline (v6 structure, verified correct in r6)
// with the register cap REMOVED. r6's __launch_bounds__(256,4) forced
// VGPR=64 -> ~164 B/thread scratch spill (WRITE_SIZE 2.2->45 MB, FETCH
// +45 MB reload) -> 141 us. (256,2) lets the allocator use ~100 VGPR;
// HW occupancy steps at 128 (m69), so a ~100-VGPR kernel still gets
// 16 waves/CU = 4 blocks/CU — double v2's residency, zero spill.
//
// Structure recap: each wave owns j-pair {2wv,2wv+1} END-TO-END:
//   score (lane=row, all 64 rows) -> e (wave-local es scratch, published
//   by lgkmcnt(0) only — NO barrier) -> accum of best[j-pair] with lanes
//   remapped to (colgroup cg=lane&15, row-quarter rs=lane>>4).
// One barrier per chunk (buffer publish only). Zero LDS bank conflicts
// (measured r6). Depth-1 staging: stage(ch+1) at top, vmcnt(0) at end —
// window = full score+accum compute.
//
// Swizzle invariant (from the DMA): LDS[row][g] = global[row][g^(row&15)]
//   score reads global group c  -> LDS group c ^ (lane&15)
//   accum reads global group cg -> LDS group cg ^ (w&15)
__global__ __launch_bounds__(256, 2) void k12_fused(const float* __restrict__ wm,
    const float* __restrict__ wcg, const float* __restrict__ w1g,
    const float* __restrict__ Ag, float* __restrict__ bpart, float* __restrict__ stats)
{
  __shared__ __align__(16) float xs[2][64 * 64];   // 32768 B
  __shared__ __align__(16) float es[4][64 * 2];    // 2048 B (per-wave scratch)

  const int tid = threadIdx.x;
  const int b = blockIdx.x, h = blockIdx.y;
  const int lane = tid & 63;
  const int wvu = __builtin_amdgcn_readfirstlane(tid >> 6);  // wave id (uniform)
  const int j0  = wvu * 2;                                   // this wave's j-pair
  const int wm15 = lane & 15;                                // score swizzle key (row&15)
  const int cg = lane & 15, rs = lane >> 4;                  // accum mapping
  const int rl = lane >> 4, pcg = lane & 15;                 // staging decomposition

  const float* wmb = wm + (size_t)b * (W_*L_) + (size_t)h * (512*L_);

  float acc0[4] = {0.f, 0.f, 0.f, 0.f};   // best[j0][cg*4..+3]
  float acc1[4] = {0.f, 0.f, 0.f, 0.f};   // best[j0+1][cg*4..+3]
  float esum[2] = {0.f, 0.f}, msum[2] = {0.f, 0.f}, m0v[2];

  auto stage = [&](const float* csrc, float* ldst) {
    #pragma unroll
    for (int k = 0; k < 4; ++k) {
      const int grow = wvu*16 + k*4 + rl;
      const int lcg  = pcg ^ (k*4 + rl);         // (grow&15) == k*4+rl
      __builtin_amdgcn_global_load_lds(
          (gas_ptr)(csrc + grow*64 + lcg*4),
          (las_ptr)(ldst + (wvu*16 + k*4)*64), 16, 0, 0);
    }
  };

  // ---- prologue: stage chunk 0 (one-time full drain; ~1 DMA latency)
  stage(wmb, &xs[0][0]);
  asm volatile("s_waitcnt vmcnt(0)" ::: "memory");
  __builtin_amdgcn_s_barrier();

  for (int ch = 0; ch < 8; ++ch) {
    float* xb = &xs[ch & 1][0];

    // ---- issue staging of chunk ch+1 (drained at END of this chunk:
    //      window = the whole score+accum compute, no barrier between)
    if (ch < 7)
      stage(wmb + (ch+1) * (64*L_), &xs[(ch+1) & 1][0]);

    // ---- score: lane owns row w=lane, wave owns j-pair
    float a10 = 0.f, a11 = 0.f, a20 = 0.f, a21 = 0.f;
    #pragma unroll
    for (int c = 0; c < 16; ++c) {
      const int col = c ^ wm15;
      float4 x = *(const float4*)&xb[lane*64 + col*4];
      float4 xq;
      xq.x = x.x*x.x; xq.y = x.y*x.y; xq.z = x.z*x.z; xq.w = x.w*x.w;
      float4 wc0 = *(const float4*)(wcg + (j0  )*L_ + c*4);   // scalar (j0 uniform)
      float4 wc1 = *(const float4*)(wcg + (j0+1)*L_ + c*4);
      float4 w10 = *(const float4*)(w1g + (j0  )*L_ + c*4);
      float4 w11 = *(const float4*)(w1g + (j0+1)*L_ + c*4);
      a10 = fmaf(wc0.x, x.x, a10); a10 = fmaf(wc0.y, x.y, a10);
      a10 = fmaf(wc0.z, x.z, a10); a10 = fmaf(wc0.w, x.w, a10);
      a11 = fmaf(wc1.x, x.x, a11); a11 = fmaf(wc1.y, x.y, a11);
      a11 = fmaf(wc1.z, x.z, a11); a11 = fmaf(wc1.w, x.w, a11);
      a20 = fmaf(w10.x, xq.x, a20); a20 = fmaf(w10.y, xq.y, a20);
      a20 = fmaf(w10.z, xq.z, a20); a20 = fmaf(w10.w, xq.w, a20);
      a21 = fmaf(w11.x, xq.x, a21); a21 = fmaf(w11.y, xq.y, a21);
      a21 = fmaf(w11.w, xq.w, a21); a21 = fmaf(w11.z, xq.z, a21);
    }
    float s0v = Ag[j0]   + a10 + a20;   // wcg already holds -2*w1*c
    float s1v = Ag[j0+1] + a11 + a21;

    if (ch == 0) {   // stabilizer: pure wave-reduce (scores >= 0, chunk-0 min safe)
      float mn0 = s0v, mn1 = s1v;
      #pragma unroll
      for (int off = 1; off < 64; off <<= 1) {
        mn0 = fminf(mn0, __shfl_xor(mn0, off));
        mn1 = fminf(mn1, __shfl_xor(mn1, off));
      }
      m0v[0] = mn0; m0v[1] = mn1;
    }

    float e0 = __expf(m0v[0] - s0v);
    float e1 = __expf(m0v[1] - s1v);
    esum[0] += e0; msum[0] = fmaf(e0, s0v, msum[0]);
    esum[1] += e1; msum[1] = fmaf(e1, s1v, msum[1]);
    // wave-local publish: lane=row w writes (e0,e1) pair
    *(float2*)&es[wvu][lane*2] = make_float2(e0, e1);

    // wave-local wait ONLY — no barrier. Retires my es write AND my
    // score ds_reads; other waves proceed independently.
    asm volatile("s_waitcnt lgkmcnt(0)" ::: "memory");

    // ---- accum: lane (cg, rs) accumulates best[j0/j0+1][cg*4..+3]
    //      over rows w = rs*16 .. rs*16+15 of this chunk.
    #pragma unroll
    for (int it = 0; it < 16; it += 2) {
      const int w0 = rs*16 + it;
      float4 e4 = *(const float4*)&es[wvu][w0*2];     // e0,e1 of w0 and w0+1 (broadcast)
      float4 xA = *(const float4*)&xb[w0*64     + (cg ^ ( w0    & 15))*4];
      float4 xB = *(const float4*)&xb[(w0+1)*64 + (cg ^ ((w0+1) & 15))*4];
      acc0[0] = fmaf(e4.x, xA.x, acc0[0]); acc0[1] = fmaf(e4.x, xA.y, acc0[1]);
      acc0[2] = fmaf(e4.x, xA.z, acc0[2]); acc0[3] = fmaf(e4.x, xA.w, acc0[3]);
      acc1[0] = fmaf(e4.y, xA.x, acc1[0]); acc1[1] = fmaf(e4.y, xA.y, acc1[1]);
      acc1[2] = fmaf(e4.y, xA.z, acc1[2]); acc1[3] = fmaf(e4.y, xA.w, acc1[3]);
      acc0[0] = fmaf(e4.z, xB.x, acc0[0]); acc0[1] = fmaf(e4.z, xB.y, acc0[1]);
      acc0[2] = fmaf(e4.z, xB.z, acc0[2]); acc0[3] = fmaf(e4.z, xB.w, acc0[3]);
      acc1[0] = fmaf(e4.w, xB.x, acc1[0]); acc1[1] = fmaf(e4.w, xB.y, acc1[1]);
      acc1[2] = fmaf(e4.w, xB.z, acc1[2]); acc1[3] = fmaf(e4.w, xB.w, acc1[3]);
    }

    // end-of-chunk: my LDS reads retired (buffer + es recyclable),
    // next chunk's DMA complete, then publish across waves.
    if (ch < 7) {
      asm volatile("s_waitcnt vmcnt(0) lgkmcnt(0)" ::: "memory");
      __builtin_amdgcn_s_barrier();
    }
  }

  // ---- stats: wave-local reduce, lane 0 writes both j's
  #pragma unroll
  for (int u = 0; u < 2; ++u) {
    float e = esum[u], m = msum[u];
    #pragma unroll
    for (int off = 1; off < 64; off <<= 1) {
      e += __shfl_xor(e, off);
      m += __shfl_xor(m, off);
    }
    if (lane == 0) {
      float* st = stats + (((size_t)h*B_ + b)*J_ + (j0+u))*4;
      st[0] = m0v[u]; st[1] = e; st[2] = m;
    }
  }

  // ---- epilogue: fold the 4 row-quarters (rs) — pure shuffle, no LDS
  #pragma unroll
  for (int q = 0; q < 4; ++q) {
    acc0[q] += __shfl_xor(acc0[q], 16);
    acc0[q] += __shfl_xor(acc0[q], 32);
    acc1[q] += __shfl_xor(acc1[q], 16);
    acc1[q] += __shfl_xor(acc1[q], 32);
  }
  if (lane < 16) {   // lane == cg
    float* bp0 = &bpart[(((size_t)h*J_ + j0    )*B_ + b)*L_ + cg*4];
    float* bp1 = &bpart[(((size_t)h*J_ + j0 + 1)*B_ + b)*L_ + cg*4];
    *(float4*)bp0 = make_float4(acc0[0], acc0[1], acc0[2], acc0[3]);
    *(float4*)bp1 = make_float4(acc1[0], acc1[1], acc1[2], acc1[3]);
  }
}

// ---------------------------------------------------------------- K2b: combine halves
__global__ __launch_bounds__(128) void k2b_combine(const float* __restrict__ bpart,
    const float* __restrict__ stats, float* __restrict__ best, float* __restrict__ conf)
{
  __shared__ float mred[J_];
  const int b = blockIdx.x, tid = threadIdx.x;
  const int j = tid >> 4, q = tid & 15;
  const float* st0 = stats + ((size_t)b*J_ + j)*4;
  const float* st1 = stats + (((size_t)B_ + b)*J_ + j)*4;
  float m0a = st0[0], E0 = st0[1], M0 = st0[2];
  float m0b = st1[0], E1 = st1[1], M1 = st1[2];
  float M = fminf(m0a, m0b);
  float s0 = __expf(M - m0a), s1 = __expf(M - m0b);
  float E = s0*E0 + s1*E1;
  float inv = 1.f / E;
  float4 p0 = *(const float4*)&bpart[((size_t)j*B_ + b)*L_ + q*4];
  float4 p1 = *(const float4*)&bpart[(((size_t)J_ + j)*B_ + b)*L_ + q*4];
  float4 o;
  o.x = (s0*p0.x + s1*p1.x) * inv;
  o.y = (s0*p0.y + s1*p1.y) * inv;
  o.z = (s0*p0.z + s1*p1.z) * inv;
  o.w = (s0*p0.w + s1*p1.w) * inv;
  *(float4*)&best[((size_t)j*B_ + b)*L_ + q*4] = o;
  if (q == 0) mred[j] = (s0*M0 + s1*M1) * inv;
  __syncthreads();
  if (tid == 0) {
    float mq = 0.f;
    #pragma unroll
    for (int jj = 0; jj < J_; ++jj) mq += mred[jj];
    conf[b] = __expf(-mq);
  }
}

// ---------------------------------------------------------------- K3: slot path, 4-way b ILP, no max-stabilizer
__global__ __launch_bounds__(256) void k3_slot(const float* __restrict__ slot_w,
    const float* __restrict__ slot_b, const float* __restrict__ best,
    float* __restrict__ partial)
{
  const int bx = blockIdx.y;            // (j, lgroup)
  const int j = bx >> 3, lg = bx & 7;
  const int bc = blockIdx.x;            // b-chunk fast dim -> L2 reuse
  const int tid = threadIdx.x;
  const int wv = tid >> 6, lane = tid & 63;
  const int l2 = lane >> 5, i = lane & 31;
  const int l = lg*8 + wv*2 + l2;
  const int r = l*I_ + i;

  const float* swr = slot_w + ((size_t)j*(L_*I_) + r) * L_;
  float sw[L_];
  #pragma unroll
  for (int c = 0; c < 16; ++c) {
    float4 t = ((const float4*)swr)[c];
    sw[c*4+0] = t.x; sw[c*4+1] = t.y; sw[c*4+2] = t.z; sw[c*4+3] = t.w;
  }
  const float sb = slot_b[j*(L_*I_) + r];
  const float* bestj = best + (size_t)j * B_ * L_;
  float* pout = partial + (size_t)bx * (B_*I_);
  const int lidx = lg*8 + wv*2;

  for (int bi = 0; bi < 32; bi += 4) {
    const int b0 = bc*32 + bi;
    const float* bw[4];
    #pragma unroll
    for (int u = 0; u < 4; ++u) bw[u] = bestj + (size_t)(b0+u) * L_;  // uniform -> s_load
    float pa[4], pb[4];
    #pragma unroll
    for (int u = 0; u < 4; ++u) { pa[u] = sb; pb[u] = 0.f; }
    #pragma unroll
    for (int c = 0; c < L_; c += 2) {
      #pragma unroll
      for (int u = 0; u < 4; ++u) {
        pa[u] = fmaf(bw[u][c+0], sw[c+0], pa[u]);
        pb[u] = fmaf(bw[u][c+1], sw[c+1], pb[u]);
      }
    }
    float e[4], sm[4];
    #pragma unroll
    for (int u = 0; u < 4; ++u) { e[u] = __expf(pa[u] + pb[u]); sm[u] = e[u]; }
    #pragma unroll
    for (int mask = 16; mask; mask >>= 1)
      #pragma unroll
      for (int u = 0; u < 4; ++u) sm[u] += __shfl_xor(sm[u], mask);
    float cv[4];
    #pragma unroll
    for (int u = 0; u < 4; ++u) {
      float bv = l2 ? bw[u][lidx+1] : bw[u][lidx];
      cv[u] = (e[u] / sm[u]) * bv;
    }
    #pragma unroll
    for (int u = 0; u < 4; ++u) cv[u] += __shfl_xor(cv[u], 32);
    if (l2 == 0) {
      #pragma unroll
      for (int u = 0; u < 4; ++u)
        pout[(size_t)(b0+u)*I_ + i] = cv[u];
    }
  }
}

// ---------------------------------------------------------------- K4: reduce + body + head + confidence
__global__ __launch_bounds__(128) void k4_head(const float* __restrict__ partial,
    const float* __restrict__ best, const float* __restrict__ gammas,
    const float* __restrict__ body_w, const float* __restrict__ body_b,
    const float* __restrict__ head_w, const float* __restrict__ head_b,
    const float* __restrict__ conf, float* __restrict__ out)
{
  __shared__ float gavg[J_];
  __shared__ float cvred[4][I_];
  __shared__ float cvf[I_];
  const int b = blockIdx.x, tid = threadIdx.x;
  const int i = tid & 31, q = tid >> 5;
  if (tid < J_) {
    float gsum = 0.f;
    for (int l = 0; l < L_; ++l) {
      float g = gammas[tid*L_ + l];
      gsum += fminf(fmaxf(g, 0.f), 1.f);
    }
    gavg[tid] = gsum * (1.f / L_);
  }
  __syncthreads();

  float acc = 0.f;
  for (int s = q; s < 64; s += 4)
    acc += partial[((size_t)s*B_ + b)*I_ + i];

  #pragma unroll
  for (int u = 0; u < 2; ++u) {
    const int j = q + u*4;
    const float* bwv  = best + ((size_t)j*B_ + b)*L_;
    const float* wrow = body_w + (size_t)(j*I_ + i)*L_;
    float d0 = body_b[j*I_ + i], d1 = 0.f, d2 = 0.f, d3 = 0.f;
    #pragma unroll
    for (int c = 0; c < L_; c += 4) {
      d0 = fmaf(bwv[c+0], wrow[c+0], d0);
      d1 = fmaf(bwv[c+1], wrow[c+1], d1);
      d2 = fmaf(bwv[c+2], wrow[c+2], d2);
      d3 = fmaf(bwv[c+3], wrow[c+3], d3);
    }
    acc = fmaf(gavg[j], (d0 + d1) + (d2 + d3), acc);
  }
  cvred[q][i] = acc;
  __syncthreads();
  if (tid < I_)
    cvf[i] = cvred[0][i] + cvred[1][i] + cvred[2][i] + cvred[3][i];
  __syncthreads();
  float oacc = head_b[tid];
  #pragma unroll
  for (int i2 = 0; i2 < I_; ++i2) oacc = fmaf(cvf[i2], head_w[tid*I_ + i2], oacc);
  out[(size_t)b*O_ + tid] = conf[b] * oacc;
}

extern "C" void kernel_launch(void* const* d_in, const int* in_sizes, int n_in,
                              void* d_out, int out_size, void* d_ws, size_t ws_size,
                              hipStream_t stream) {
  const float* wm        = (const float*)d_in[0];
  const float* constants = (const float*)d_in[1];
  const float* gammas    = (const float*)d_in[2];
  const float* body_w    = (const float*)d_in[3];
  const float* body_b    = (const float*)d_in[4];
  const float* slot_w    = (const float*)d_in[5];
  const float* slot_b    = (const float*)d_in[6];
  const float* head_w    = (const float*)d_in[7];
  const float* head_b    = (const float*)d_in[8];
  float* out = (float*)d_out;

  float* ws      = (float*)d_ws;
  float* wcg     = ws;
  float* w1g     = wcg + J_*L_;
  float* Ag      = w1g + J_*L_;
  float* best    = Ag + 16;
  float* conf    = best + (size_t)J_*B_*L_;
  float* partial = conf + B_;
  float* bpart   = partial + (size_t)64*B_*I_;
  float* stats   = bpart + (size_t)2*J_*B_*L_;

  hipLaunchKernelGGL(k0_prep, dim3(1), dim3(64), 0, stream,
                     constants, gammas, wcg, w1g, Ag);
  hipLaunchKernelGGL(k12_fused, dim3(B_, 2), dim3(256), 0, stream,
                     wm, wcg, w1g, Ag, bpart, stats);
  hipLaunchKernelGGL(k2b_combine, dim3(B_), dim3(128), 0, stream,
                     bpart, stats, best, conf);
  hipLaunchKernelGGL(k3_slot, dim3(16, 64), dim3(256), 0, stream,
                     slot_w, slot_b, best, partial);
  hipLaunchKernelGGL(k4_head, dim3(B_), dim3(128), 0, stream,
                     partial, best, gammas, body_w, body_b, head_w, head_b, conf, out);
}

// Round 8
// 256.370 us; speedup vs baseline: 1.3154x; 1.1035x over previous
//
#include <hip/hip_runtime.h>
#include <cstdint>
#include <cstddef>

#define B_ 512
#define W_ 1024
#define L_ 64
#define J_ 8
#define I_ 32
#define O_ 128
#define H_ 8            // wm split: 8 chunks of 64 rows, one per block

// ws layout (floats):
// wcg   : [J][L]        = 512   (holds -2*(1-g)*c)
// w1g   : [J][L]        = 512
// Ag    : [J] (+pad)    = 16
// best  : [J][B][L]     = 262144
// conf  : [B]           = 512
// partial:[64][B][I]    = 1048576
// bpart : [H][J][B][L]  = 2097152
// stats : [H][B][J][4]  = 65536

typedef const __attribute__((address_space(1))) void* gas_ptr;
typedef __attribute__((address_space(3))) void* las_ptr;

// ---------------------------------------------------------------- K0
__global__ __launch_bounds__(64) void k0_prep(const float* __restrict__ constants,
    const float* __restrict__ gammas, float* __restrict__ wcg,
    float* __restrict__ w1g, float* __restrict__ Ag)
{
  const int l = threadIdx.x;
  #pragma unroll
  for (int j = 0; j < J_; ++j) {
    float g = gammas[j*L_ + l];
    g = fminf(fmaxf(g, 0.f), 1.f);
    float c = constants[j*L_ + l];
    float w1 = 1.f - g;
    w1g[j*L_ + l] = w1;
    wcg[j*L_ + l] = -2.f * w1 * c;   // fold the -2 of the cross term here
  }
  if (l < J_) {
    float a = 0.f;
    for (int c = 0; c < L_; ++c) {
      float g = gammas[l*L_ + c];
      g = fminf(fmaxf(g, 0.f), 1.f);
      float cc = constants[l*L_ + c];
      a += (1.f - g) * cc * cc;
    }
    Ag[l] = a;
  }
}

// ---------------------------------------------------------------- K12 v7:
// FLATTENED: grid (B, 8) — each block owns ONE 64-row chunk. The serial
// 8-chunk stage->wait->compute chain (which pinned k12 at 70-78 us
// across v1/v2/v6b — intra-block pipelining failed 3x on registers) is
// GONE. Latency hiding is now inter-block TLP: 4096 blocks, ~4
// co-resident/CU (16.5 KB LDS, ~85 VGPR); while one block waits on its
// single DMA, three others compute. One vmcnt wait + one barrier per
// block LIFETIME.
//
// Wave-independent j-pair structure (v6b, verified r6/r7, 0 bank
// conflicts): wave owns j-pair {2wv,2wv+1} end-to-end; score (lane=row,
// 64 rows) -> e in wave-local es (lgkmcnt(0) publish, no barrier) ->
// accum with lanes remapped to (colgroup cg, row-quarter rs) -> pure
// shuffle epilogue.
// Swizzle invariant (from DMA): LDS[row][g] = global[row][g^(row&15)]
//   score reads global group c  -> LDS group c ^ (lane&15)
//   accum reads global group cg -> LDS group cg ^ (w&15)
__global__ __launch_bounds__(256, 2) void k12_fused(const float* __restrict__ wm,
    const float* __restrict__ wcg, const float* __restrict__ w1g,
    const float* __restrict__ Ag, float* __restrict__ bpart, float* __restrict__ stats)
{
  __shared__ __align__(16) float xs[64 * 64];      // 16384 B
  __shared__ __align__(16) float es[4][64 * 2];    // 2048 B (per-wave scratch)

  const int tid = threadIdx.x;
  const int b = blockIdx.x, h = blockIdx.y;
  const int lane = tid & 63;
  const int wvu = __builtin_amdgcn_readfirstlane(tid >> 6);  // wave id (uniform)
  const int j0  = wvu * 2;                                   // this wave's j-pair
  const int wm15 = lane & 15;                                // score swizzle key (row&15)
  const int cg = lane & 15, rs = lane >> 4;                  // accum mapping
  const int rl = lane >> 4, pcg = lane & 15;                 // staging decomposition

  const float* wmb = wm + (size_t)b * (W_*L_) + (size_t)h * (64*L_);

  // ---- stage this block's 64-row chunk (one-time)
  #pragma unroll
  for (int k = 0; k < 4; ++k) {
    const int grow = wvu*16 + k*4 + rl;
    const int lcg  = pcg ^ (k*4 + rl);           // (grow&15) == k*4+rl
    __builtin_amdgcn_global_load_lds(
        (gas_ptr)(wmb + grow*64 + lcg*4),
        (las_ptr)&xs[(wvu*16 + k*4)*64], 16, 0, 0);
  }
  asm volatile("s_waitcnt vmcnt(0)" ::: "memory");
  __builtin_amdgcn_s_barrier();                  // the ONLY barrier

  // ---- score: lane owns row w=lane, wave owns j-pair
  float a10 = 0.f, a11 = 0.f, a20 = 0.f, a21 = 0.f;
  #pragma unroll
  for (int c = 0; c < 16; ++c) {
    const int col = c ^ wm15;
    float4 x = *(const float4*)&xs[lane*64 + col*4];
    float4 xq;
    xq.x = x.x*x.x; xq.y = x.y*x.y; xq.z = x.z*x.z; xq.w = x.w*x.w;
    float4 wc0 = *(const float4*)(wcg + (j0  )*L_ + c*4);   // scalar (j0 uniform)
    float4 wc1 = *(const float4*)(wcg + (j0+1)*L_ + c*4);
    float4 w10 = *(const float4*)(w1g + (j0  )*L_ + c*4);
    float4 w11 = *(const float4*)(w1g + (j0+1)*L_ + c*4);
    a10 = fmaf(wc0.x, x.x, a10); a10 = fmaf(wc0.y, x.y, a10);
    a10 = fmaf(wc0.z, x.z, a10); a10 = fmaf(wc0.w, x.w, a10);
    a11 = fmaf(wc1.x, x.x, a11); a11 = fmaf(wc1.y, x.y, a11);
    a11 = fmaf(wc1.z, x.z, a11); a11 = fmaf(wc1.w, x.w, a11);
    a20 = fmaf(w10.x, xq.x, a20); a20 = fmaf(w10.y, xq.y, a20);
    a20 = fmaf(w10.z, xq.z, a20); a20 = fmaf(w10.w, xq.w, a20);
    a21 = fmaf(w11.x, xq.x, a21); a21 = fmaf(w11.y, xq.y, a21);
    a21 = fmaf(w11.z, xq.z, a21); a21 = fmaf(w11.w, xq.w, a21);
  }
  float s0v = Ag[j0]   + a10 + a20;   // wcg already holds -2*w1*c
  float s1v = Ag[j0+1] + a11 + a21;

  // stabilizer: min over this block's 64 rows (pure wave-reduce)
  float mn0 = s0v, mn1 = s1v;
  #pragma unroll
  for (int off = 1; off < 64; off <<= 1) {
    mn0 = fminf(mn0, __shfl_xor(mn0, off));
    mn1 = fminf(mn1, __shfl_xor(mn1, off));
  }

  float e0 = __expf(mn0 - s0v);
  float e1 = __expf(mn1 - s1v);
  float esum0 = e0, esum1 = e1;
  float msum0 = e0 * s0v, msum1 = e1 * s1v;
  // wave-local publish: lane=row w writes (e0,e1) pair
  *(float2*)&es[wvu][lane*2] = make_float2(e0, e1);
  asm volatile("s_waitcnt lgkmcnt(0)" ::: "memory");   // wave-local, no barrier

  // ---- accum: lane (cg, rs) accumulates best[j0/j0+1][cg*4..+3]
  //      over rows w = rs*16 .. rs*16+15.
  float acc0[4] = {0.f, 0.f, 0.f, 0.f};
  float acc1[4] = {0.f, 0.f, 0.f, 0.f};
  #pragma unroll
  for (int it = 0; it < 16; it += 2) {
    const int w0 = rs*16 + it;
    float4 e4 = *(const float4*)&es[wvu][w0*2];     // e0,e1 of w0 and w0+1 (broadcast)
    float4 xA = *(const float4*)&xs[w0*64     + (cg ^ ( w0    & 15))*4];
    float4 xB = *(const float4*)&xs[(w0+1)*64 + (cg ^ ((w0+1) & 15))*4];
    acc0[0] = fmaf(e4.x, xA.x, acc0[0]); acc0[1] = fmaf(e4.x, xA.y, acc0[1]);
    acc0[2] = fmaf(e4.x, xA.z, acc0[2]); acc0[3] = fmaf(e4.x, xA.w, acc0[3]);
    acc1[0] = fmaf(e4.y, xA.x, acc1[0]); acc1[1] = fmaf(e4.y, xA.y, acc1[1]);
    acc1[2] = fmaf(e4.y, xA.z, acc1[2]); acc1[3] = fmaf(e4.y, xA.w, acc1[3]);
    acc0[0] = fmaf(e4.z, xB.x, acc0[0]); acc0[1] = fmaf(e4.z, xB.y, acc0[1]);
    acc0[2] = fmaf(e4.z, xB.z, acc0[2]); acc0[3] = fmaf(e4.z, xB.w, acc0[3]);
    acc1[0] = fmaf(e4.w, xB.x, acc1[0]); acc1[1] = fmaf(e4.w, xB.y, acc1[1]);
    acc1[2] = fmaf(e4.w, xB.z, acc1[2]); acc1[3] = fmaf(e4.w, xB.w, acc1[3]);
  }

  // ---- stats: wave-local reduce, lane 0 writes both j's
  {
    float ea = esum0, ma = msum0, eb = esum1, mb = msum1;
    #pragma unroll
    for (int off = 1; off < 64; off <<= 1) {
      ea += __shfl_xor(ea, off); ma += __shfl_xor(ma, off);
      eb += __shfl_xor(eb, off); mb += __shfl_xor(mb, off);
    }
    if (lane == 0) {
      float* st0 = stats + (((size_t)h*B_ + b)*J_ + j0)*4;
      st0[0] = mn0; st0[1] = ea; st0[2] = ma;
      float* st1 = stats + (((size_t)h*B_ + b)*J_ + j0 + 1)*4;
      st1[0] = mn1; st1[1] = eb; st1[2] = mb;
    }
  }

  // ---- epilogue: fold the 4 row-quarters (rs) — pure shuffle, no LDS
  #pragma unroll
  for (int q = 0; q < 4; ++q) {
    acc0[q] += __shfl_xor(acc0[q], 16);
    acc0[q] += __shfl_xor(acc0[q], 32);
    acc1[q] += __shfl_xor(acc1[q], 16);
    acc1[q] += __shfl_xor(acc1[q], 32);
  }
  if (lane < 16) {   // lane == cg
    float* bp0 = &bpart[(((size_t)h*J_ + j0    )*B_ + b)*L_ + cg*4];
    float* bp1 = &bpart[(((size_t)h*J_ + j0 + 1)*B_ + b)*L_ + cg*4];
    *(float4*)bp0 = make_float4(acc0[0], acc0[1], acc0[2], acc0[3]);
    *(float4*)bp1 = make_float4(acc1[0], acc1[1], acc1[2], acc1[3]);
  }
}

// ---------------------------------------------------------------- K2b: combine H_ partials
__global__ __launch_bounds__(128) void k2b_combine(const float* __restrict__ bpart,
    const float* __restrict__ stats, float* __restrict__ best, float* __restrict__ conf)
{
  __shared__ float mred[J_];
  const int b = blockIdx.x, tid = threadIdx.x;
  const int j = tid >> 4, q = tid & 15;

  float m0[H_], E[H_], Mq[H_];
  #pragma unroll
  for (int u = 0; u < H_; ++u) {
    const float* st = stats + (((size_t)u*B_ + b)*J_ + j)*4;
    m0[u] = st[0]; E[u] = st[1]; Mq[u] = st[2];
  }
  float M = m0[0];
  #pragma unroll
  for (int u = 1; u < H_; ++u) M = fminf(M, m0[u]);
  float s[H_], Esum = 0.f, Msum = 0.f;
  #pragma unroll
  for (int u = 0; u < H_; ++u) {
    s[u] = __expf(M - m0[u]);
    Esum = fmaf(s[u], E[u], Esum);
    Msum = fmaf(s[u], Mq[u], Msum);
  }
  float inv = 1.f / Esum;
  float4 o = make_float4(0.f, 0.f, 0.f, 0.f);
  #pragma unroll
  for (int u = 0; u < H_; ++u) {
    float4 p = *(const float4*)&bpart[(((size_t)u*J_ + j)*B_ + b)*L_ + q*4];
    o.x = fmaf(s[u], p.x, o.x); o.y = fmaf(s[u], p.y, o.y);
    o.z = fmaf(s[u], p.z, o.z); o.w = fmaf(s[u], p.w, o.w);
  }
  o.x *= inv; o.y *= inv; o.z *= inv; o.w *= inv;
  *(float4*)&best[((size_t)j*B_ + b)*L_ + q*4] = o;
  if (q == 0) mred[j] = Msum * inv;
  __syncthreads();
  if (tid == 0) {
    float mq = 0.f;
    #pragma unroll
    for (int jj = 0; jj < J_; ++jj) mq += mred[jj];
    conf[b] = __expf(-mq);
  }
}

// ---------------------------------------------------------------- K3: slot path, 4-way b ILP, no max-stabilizer
__global__ __launch_bounds__(256) void k3_slot(const float* __restrict__ slot_w,
    const float* __restrict__ slot_b, const float* __restrict__ best,
    float* __restrict__ partial)
{
  const int bx = blockIdx.y;            // (j, lgroup)
  const int j = bx >> 3, lg = bx & 7;
  const int bc = blockIdx.x;            // b-chunk fast dim -> L2 reuse
  const int tid = threadIdx.x;
  const int wv = tid >> 6, lane = tid & 63;
  const int l2 = lane >> 5, i = lane & 31;
  const int l = lg*8 + wv*2 + l2;
  const int r = l*I_ + i;

  const float* swr = slot_w + ((size_t)j*(L_*I_) + r) * L_;
  float sw[L_];
  #pragma unroll
  for (int c = 0; c < 16; ++c) {
    float4 t = ((const float4*)swr)[c];
    sw[c*4+0] = t.x; sw[c*4+1] = t.y; sw[c*4+2] = t.z; sw[c*4+3] = t.w;
  }
  const float sb = slot_b[j*(L_*I_) + r];
  const float* bestj = best + (size_t)j * B_ * L_;
  float* pout = partial + (size_t)bx * (B_*I_);
  const int lidx = lg*8 + wv*2;

  for (int bi = 0; bi < 32; bi += 4) {
    const int b0 = bc*32 + bi;
    const float* bw[4];
    #pragma unroll
    for (int u = 0; u < 4; ++u) bw[u] = bestj + (size_t)(b0+u) * L_;  // uniform -> s_load
    float pa[4], pb[4];
    #pragma unroll
    for (int u = 0; u < 4; ++u) { pa[u] = sb; pb[u] = 0.f; }
    #pragma unroll
    for (int c = 0; c < L_; c += 2) {
      #pragma unroll
      for (int u = 0; u < 4; ++u) {
        pa[u] = fmaf(bw[u][c+0], sw[c+0], pa[u]);
        pb[u] = fmaf(bw[u][c+1], sw[c+1], pb[u]);
      }
    }
    float e[4], sm[4];
    #pragma unroll
    for (int u = 0; u < 4; ++u) { e[u] = __expf(pa[u] + pb[u]); sm[u] = e[u]; }
    #pragma unroll
    for (int mask = 16; mask; mask >>= 1)
      #pragma unroll
      for (int u = 0; u < 4; ++u) sm[u] += __shfl_xor(sm[u], mask);
    float cv[4];
    #pragma unroll
    for (int u = 0; u < 4; ++u) {
      float bv = l2 ? bw[u][lidx+1] : bw[u][lidx];
      cv[u] = (e[u] / sm[u]) * bv;
    }
    #pragma unroll
    for (int u = 0; u < 4; ++u) cv[u] += __shfl_xor(cv[u], 32);
    if (l2 == 0) {
      #pragma unroll
      for (int u = 0; u < 4; ++u)
        pout[(size_t)(b0+u)*I_ + i] = cv[u];
    }
  }
}

// ---------------------------------------------------------------- K4: reduce + body + head + confidence
__global__ __launch_bounds__(128) void k4_head(const float* __restrict__ partial,
    const float* __restrict__ best, const float* __restrict__ gammas,
    const float* __restrict__ body_w, const float* __restrict__ body_b,
    const float* __restrict__ head_w, const float* __restrict__ head_b,
    const float* __restrict__ conf, float* __restrict__ out)
{
  __shared__ float gavg[J_];
  __shared__ float cvred[4][I_];
  __shared__ float cvf[I_];
  const int b = blockIdx.x, tid = threadIdx.x;
  const int i = tid & 31, q = tid >> 5;
  if (tid < J_) {
    float gsum = 0.f;
    for (int l = 0; l < L_; ++l) {
      float g = gammas[tid*L_ + l];
      gsum += fminf(fmaxf(g, 0.f), 1.f);
    }
    gavg[tid] = gsum * (1.f / L_);
  }
  __syncthreads();

  float acc = 0.f;
  for (int s = q; s < 64; s += 4)
    acc += partial[((size_t)s*B_ + b)*I_ + i];

  #pragma unroll
  for (int u = 0; u < 2; ++u) {
    const int j = q + u*4;
    const float* bwv  = best + ((size_t)j*B_ + b)*L_;
    const float* wrow = body_w + (size_t)(j*I_ + i)*L_;
    float d0 = body_b[j*I_ + i], d1 = 0.f, d2 = 0.f, d3 = 0.f;
    #pragma unroll
    for (int c = 0; c < L_; c += 4) {
      d0 = fmaf(bwv[c+0], wrow[c+0], d0);
      d1 = fmaf(bwv[c+1], wrow[c+1], d1);
      d2 = fmaf(bwv[c+2], wrow[c+2], d2);
      d3 = fmaf(bwv[c+3], wrow[c+3], d3);
    }
    acc = fmaf(gavg[j], (d0 + d1) + (d2 + d3), acc);
  }
  cvred[q][i] = acc;
  __syncthreads();
  if (tid < I_)
    cvf[i] = cvred[0][i] + cvred[1][i] + cvred[2][i] + cvred[3][i];
  __syncthreads();
  float oacc = head_b[tid];
  #pragma unroll
  for (int i2 = 0; i2 < I_; ++i2) oacc = fmaf(cvf[i2], head_w[tid*I_ + i2], oacc);
  out[(size_t)b*O_ + tid] = conf[b] * oacc;
}

extern "C" void kernel_launch(void* const* d_in, const int* in_sizes, int n_in,
                              void* d_out, int out_size, void* d_ws, size_t ws_size,
                              hipStream_t stream) {
  const float* wm        = (const float*)d_in[0];
  const float* constants = (const float*)d_in[1];
  const float* gammas    = (const float*)d_in[2];
  const float* body_w    = (const float*)d_in[3];
  const float* body_b    = (const float*)d_in[4];
  const float* slot_w    = (const float*)d_in[5];
  const float* slot_b    = (const float*)d_in[6];
  const float* head_w    = (const float*)d_in[7];
  const float* head_b    = (const float*)d_in[8];
  float* out = (float*)d_out;

  float* ws      = (float*)d_ws;
  float* wcg     = ws;
  float* w1g     = wcg + J_*L_;
  float* Ag      = w1g + J_*L_;
  float* best    = Ag + 16;
  float* conf    = best + (size_t)J_*B_*L_;
  float* partial = conf + B_;
  float* bpart   = partial + (size_t)64*B_*I_;
  float* stats   = bpart + (size_t)H_*J_*B_*L_;

  hipLaunchKernelGGL(k0_prep, dim3(1), dim3(64), 0, stream,
                     constants, gammas, wcg, w1g, Ag);
  hipLaunchKernelGGL(k12_fused, dim3(B_, H_), dim3(256), 0, stream,
                     wm, wcg, w1g, Ag, bpart, stats);
  hipLaunchKernelGGL(k2b_combine, dim3(B_), dim3(128), 0, stream,
                     bpart, stats, best, conf);
  hipLaunchKernelGGL(k3_slot, dim3(16, 64), dim3(256), 0, stream,
                     slot_w, slot_b, best, partial);
  hipLaunchKernelGGL(k4_head, dim3(B_), dim3(128), 0, stream,
                     partial, best, gammas, body_w, body_b, head_w, head_b, conf, out);
}

// Round 9
// 255.573 us; speedup vs baseline: 1.3195x; 1.0031x over previous
//
#include <hip/hip_runtime.h>
#include <cstdint>
#include <cstddef>

#define B_ 512
#define W_ 1024
#define L_ 64
#define J_ 8
#define I_ 32
#define O_ 128
#define H_ 8            // wm split: 8 chunks of 64 rows, one per block

// ws layout (floats):
// wcg   : [J][L]        = 512   (holds -2*(1-g)*c)
// w1g   : [J][L]        = 512
// Ag    : [J] (+pad)    = 16
// best  : [J][B][L]     = 262144
// conf  : [B]           = 512
// partial:[64][B][I]    = 1048576
// bpart : [H][J][B][L]  = 2097152
// stats : [H][B][J][4]  = 65536

typedef const __attribute__((address_space(1))) void* gas_ptr;
typedef __attribute__((address_space(3))) void* las_ptr;

// ---------------------------------------------------------------- K0
__global__ __launch_bounds__(64) void k0_prep(const float* __restrict__ constants,
    const float* __restrict__ gammas, float* __restrict__ wcg,
    float* __restrict__ w1g, float* __restrict__ Ag)
{
  const int l = threadIdx.x;
  #pragma unroll
  for (int j = 0; j < J_; ++j) {
    float g = gammas[j*L_ + l];
    g = fminf(fmaxf(g, 0.f), 1.f);
    float c = constants[j*L_ + l];
    float w1 = 1.f - g;
    w1g[j*L_ + l] = w1;
    wcg[j*L_ + l] = -2.f * w1 * c;   // fold the -2 of the cross term here
  }
  if (l < J_) {
    float a = 0.f;
    for (int c = 0; c < L_; ++c) {
      float g = gammas[l*L_ + c];
      g = fminf(fmaxf(g, 0.f), 1.f);
      float cc = constants[l*L_ + c];
      a += (1.f - g) * cc * cc;
    }
    Ag[l] = a;
  }
}

// ---------------------------------------------------------------- K12 v8:
// v7 (flattened grid (B,8), one 64-row chunk per block — r8: 282.9->256.4,
// k12 ~51us) with occupancy doubled: __launch_bounds__(256, 4) caps VGPR
// at 64 -> 8 blocks/CU (32 waves) instead of 4. v7's loop-free body has
// peak liveness ~50 VGPR (score: x+xq+4 accums, weights in SGPRs via
// s_load; accum: x4[8]+e4[4]+acc[8]) so 64 fits WITHOUT spill — unlike
// r6 where the same cap on the 8-chunk-loop version spilled 164 B/thread
// (loop-carried dbuf state). esum/msum regs dropped: in loop-free form
// esum==e0, msum==e0*s0v — reduced directly at the stats step.
//
// Wave-independent j-pair structure (verified r6/r7/r8, 0 bank
// conflicts): wave owns j-pair {2wv,2wv+1} end-to-end; score (lane=row,
// 64 rows) -> e in wave-local es (lgkmcnt(0) publish, no barrier) ->
// accum with lanes remapped to (colgroup cg, row-quarter rs) -> pure
// shuffle epilogue. One vmcnt wait + one barrier per block lifetime.
// Swizzle invariant (from DMA): LDS[row][g] = global[row][g^(row&15)]
//   score reads global group c  -> LDS group c ^ (lane&15)
//   accum reads global group cg -> LDS group cg ^ (w&15)
__global__ __launch_bounds__(256, 4) void k12_fused(const float* __restrict__ wm,
    const float* __restrict__ wcg, const float* __restrict__ w1g,
    const float* __restrict__ Ag, float* __restrict__ bpart, float* __restrict__ stats)
{
  __shared__ __align__(16) float xs[64 * 64];      // 16384 B
  __shared__ __align__(16) float es[4][64 * 2];    // 2048 B (per-wave scratch)

  const int tid = threadIdx.x;
  const int b = blockIdx.x, h = blockIdx.y;
  const int lane = tid & 63;
  const int wvu = __builtin_amdgcn_readfirstlane(tid >> 6);  // wave id (uniform)
  const int j0  = wvu * 2;                                   // this wave's j-pair
  const int wm15 = lane & 15;                                // score swizzle key (row&15)
  const int cg = lane & 15, rs = lane >> 4;                  // accum mapping
  const int rl = lane >> 4, pcg = lane & 15;                 // staging decomposition

  const float* wmb = wm + (size_t)b * (W_*L_) + (size_t)h * (64*L_);

  // ---- stage this block's 64-row chunk (one-time)
  #pragma unroll
  for (int k = 0; k < 4; ++k) {
    const int grow = wvu*16 + k*4 + rl;
    const int lcg  = pcg ^ (k*4 + rl);           // (grow&15) == k*4+rl
    __builtin_amdgcn_global_load_lds(
        (gas_ptr)(wmb + grow*64 + lcg*4),
        (las_ptr)&xs[(wvu*16 + k*4)*64], 16, 0, 0);
  }
  asm volatile("s_waitcnt vmcnt(0)" ::: "memory");
  __builtin_amdgcn_s_barrier();                  // the ONLY barrier

  // ---- score: lane owns row w=lane, wave owns j-pair
  float a10 = 0.f, a11 = 0.f, a20 = 0.f, a21 = 0.f;
  #pragma unroll
  for (int c = 0; c < 16; ++c) {
    const int col = c ^ wm15;
    float4 x = *(const float4*)&xs[lane*64 + col*4];
    float4 xq;
    xq.x = x.x*x.x; xq.y = x.y*x.y; xq.z = x.z*x.z; xq.w = x.w*x.w;
    float4 wc0 = *(const float4*)(wcg + (j0  )*L_ + c*4);   // scalar (j0 uniform)
    float4 wc1 = *(const float4*)(wcg + (j0+1)*L_ + c*4);
    float4 w10 = *(const float4*)(w1g + (j0  )*L_ + c*4);
    float4 w11 = *(const float4*)(w1g + (j0+1)*L_ + c*4);
    a10 = fmaf(wc0.x, x.x, a10); a10 = fmaf(wc0.y, x.y, a10);
    a10 = fmaf(wc0.z, x.z, a10); a10 = fmaf(wc0.w, x.w, a10);
    a11 = fmaf(wc1.x, x.x, a11); a11 = fmaf(wc1.y, x.y, a11);
    a11 = fmaf(wc1.z, x.z, a11); a11 = fmaf(wc1.w, x.w, a11);
    a20 = fmaf(w10.x, xq.x, a20); a20 = fmaf(w10.y, xq.y, a20);
    a20 = fmaf(w10.z, xq.z, a20); a20 = fmaf(w10.w, xq.w, a20);
    a21 = fmaf(w11.x, xq.x, a21); a21 = fmaf(w11.y, xq.y, a21);
    a21 = fmaf(w11.z, xq.z, a21); a21 = fmaf(w11.w, xq.w, a21);
  }
  float s0v = Ag[j0]   + a10 + a20;   // wcg already holds -2*w1*c
  float s1v = Ag[j0+1] + a11 + a21;

  // stabilizer: min over this block's 64 rows (pure wave-reduce)
  float mn0 = s0v, mn1 = s1v;
  #pragma unroll
  for (int off = 1; off < 64; off <<= 1) {
    mn0 = fminf(mn0, __shfl_xor(mn0, off));
    mn1 = fminf(mn1, __shfl_xor(mn1, off));
  }

  float e0 = __expf(mn0 - s0v);
  float e1 = __expf(mn1 - s1v);
  // wave-local publish: lane=row w writes (e0,e1) pair
  *(float2*)&es[wvu][lane*2] = make_float2(e0, e1);
  asm volatile("s_waitcnt lgkmcnt(0)" ::: "memory");   // wave-local, no barrier

  // ---- accum: lane (cg, rs) accumulates best[j0/j0+1][cg*4..+3]
  //      over rows w = rs*16 .. rs*16+15.
  float acc0[4] = {0.f, 0.f, 0.f, 0.f};
  float acc1[4] = {0.f, 0.f, 0.f, 0.f};
  #pragma unroll
  for (int it = 0; it < 16; it += 2) {
    const int w0 = rs*16 + it;
    float4 e4 = *(const float4*)&es[wvu][w0*2];     // e0,e1 of w0 and w0+1 (broadcast)
    float4 xA = *(const float4*)&xs[w0*64     + (cg ^ ( w0    & 15))*4];
    float4 xB = *(const float4*)&xs[(w0+1)*64 + (cg ^ ((w0+1) & 15))*4];
    acc0[0] = fmaf(e4.x, xA.x, acc0[0]); acc0[1] = fmaf(e4.x, xA.y, acc0[1]);
    acc0[2] = fmaf(e4.x, xA.z, acc0[2]); acc0[3] = fmaf(e4.x, xA.w, acc0[3]);
    acc1[0] = fmaf(e4.y, xA.x, acc1[0]); acc1[1] = fmaf(e4.y, xA.y, acc1[1]);
    acc1[2] = fmaf(e4.y, xA.z, acc1[2]); acc1[3] = fmaf(e4.y, xA.w, acc1[3]);
    acc0[0] = fmaf(e4.z, xB.x, acc0[0]); acc0[1] = fmaf(e4.z, xB.y, acc0[1]);
    acc0[2] = fmaf(e4.z, xB.z, acc0[2]); acc0[3] = fmaf(e4.z, xB.w, acc0[3]);
    acc1[0] = fmaf(e4.w, xB.x, acc1[0]); acc1[1] = fmaf(e4.w, xB.y, acc1[1]);
    acc1[2] = fmaf(e4.w, xB.z, acc1[2]); acc1[3] = fmaf(e4.w, xB.w, acc1[3]);
  }

  // ---- stats: reduce e and e*s over the wave's 64 rows, lane 0 writes
  {
    float ea = e0, ma = e0 * s0v, eb = e1, mb = e1 * s1v;
    #pragma unroll
    for (int off = 1; off < 64; off <<= 1) {
      ea += __shfl_xor(ea, off); ma += __shfl_xor(ma, off);
      eb += __shfl_xor(eb, off); mb += __shfl_xor(mb, off);
    }
    if (lane == 0) {
      float* st0 = stats + (((size_t)h*B_ + b)*J_ + j0)*4;
      st0[0] = mn0; st0[1] = ea; st0[2] = ma;
      float* st1 = stats + (((size_t)h*B_ + b)*J_ + j0 + 1)*4;
      st1[0] = mn1; st1[1] = eb; st1[2] = mb;
    }
  }

  // ---- epilogue: fold the 4 row-quarters (rs) — pure shuffle, no LDS
  #pragma unroll
  for (int q = 0; q < 4; ++q) {
    acc0[q] += __shfl_xor(acc0[q], 16);
    acc0[q] += __shfl_xor(acc0[q], 32);
    acc1[q] += __shfl_xor(acc1[q], 16);
    acc1[q] += __shfl_xor(acc1[q], 32);
  }
  if (lane < 16) {   // lane == cg
    float* bp0 = &bpart[(((size_t)h*J_ + j0    )*B_ + b)*L_ + cg*4];
    float* bp1 = &bpart[(((size_t)h*J_ + j0 + 1)*B_ + b)*L_ + cg*4];
    *(float4*)bp0 = make_float4(acc0[0], acc0[1], acc0[2], acc0[3]);
    *(float4*)bp1 = make_float4(acc1[0], acc1[1], acc1[2], acc1[3]);
  }
}

// ---------------------------------------------------------------- K2b: combine H_ partials
__global__ __launch_bounds__(128) void k2b_combine(const float* __restrict__ bpart,
    const float* __restrict__ stats, float* __restrict__ best, float* __restrict__ conf)
{
  __shared__ float mred[J_];
  const int b = blockIdx.x, tid = threadIdx.x;
  const int j = tid >> 4, q = tid & 15;

  float m0[H_], E[H_], Mq[H_];
  #pragma unroll
  for (int u = 0; u < H_; ++u) {
    const float* st = stats + (((size_t)u*B_ + b)*J_ + j)*4;
    m0[u] = st[0]; E[u] = st[1]; Mq[u] = st[2];
  }
  float M = m0[0];
  #pragma unroll
  for (int u = 1; u < H_; ++u) M = fminf(M, m0[u]);
  float s[H_], Esum = 0.f, Msum = 0.f;
  #pragma unroll
  for (int u = 0; u < H_; ++u) {
    s[u] = __expf(M - m0[u]);
    Esum = fmaf(s[u], E[u], Esum);
    Msum = fmaf(s[u], Mq[u], Msum);
  }
  float inv = 1.f / Esum;
  float4 o = make_float4(0.f, 0.f, 0.f, 0.f);
  #pragma unroll
  for (int u = 0; u < H_; ++u) {
    float4 p = *(const float4*)&bpart[(((size_t)u*J_ + j)*B_ + b)*L_ + q*4];
    o.x = fmaf(s[u], p.x, o.x); o.y = fmaf(s[u], p.y, o.y);
    o.z = fmaf(s[u], p.z, o.z); o.w = fmaf(s[u], p.w, o.w);
  }
  o.x *= inv; o.y *= inv; o.z *= inv; o.w *= inv;
  *(float4*)&best[((size_t)j*B_ + b)*L_ + q*4] = o;
  if (q == 0) mred[j] = Msum * inv;
  __syncthreads();
  if (tid == 0) {
    float mq = 0.f;
    #pragma unroll
    for (int jj = 0; jj < J_; ++jj) mq += mred[jj];
    conf[b] = __expf(-mq);
  }
}

// ---------------------------------------------------------------- K3: slot path, 4-way b ILP, no max-stabilizer
__global__ __launch_bounds__(256) void k3_slot(const float* __restrict__ slot_w,
    const float* __restrict__ slot_b, const float* __restrict__ best,
    float* __restrict__ partial)
{
  const int bx = blockIdx.y;            // (j, lgroup)
  const int j = bx >> 3, lg = bx & 7;
  const int bc = blockIdx.x;            // b-chunk fast dim -> L2 reuse
  const int tid = threadIdx.x;
  const int wv = tid >> 6, lane = tid & 63;
  const int l2 = lane >> 5, i = lane & 31;
  const int l = lg*8 + wv*2 + l2;
  const int r = l*I_ + i;

  const float* swr = slot_w + ((size_t)j*(L_*I_) + r) * L_;
  float sw[L_];
  #pragma unroll
  for (int c = 0; c < 16; ++c) {
    float4 t = ((const float4*)swr)[c];
    sw[c*4+0] = t.x; sw[c*4+1] = t.y; sw[c*4+2] = t.z; sw[c*4+3] = t.w;
  }
  const float sb = slot_b[j*(L_*I_) + r];
  const float* bestj = best + (size_t)j * B_ * L_;
  float* pout = partial + (size_t)bx * (B_*I_);
  const int lidx = lg*8 + wv*2;

  for (int bi = 0; bi < 32; bi += 4) {
    const int b0 = bc*32 + bi;
    const float* bw[4];
    #pragma unroll
    for (int u = 0; u < 4; ++u) bw[u] = bestj + (size_t)(b0+u) * L_;  // uniform -> s_load
    float pa[4], pb[4];
    #pragma unroll
    for (int u = 0; u < 4; ++u) { pa[u] = sb; pb[u] = 0.f; }
    #pragma unroll
    for (int c = 0; c < L_; c += 2) {
      #pragma unroll
      for (int u = 0; u < 4; ++u) {
        pa[u] = fmaf(bw[u][c+0], sw[c+0], pa[u]);
        pb[u] = fmaf(bw[u][c+1], sw[c+1], pb[u]);
      }
    }
    float e[4], sm[4];
    #pragma unroll
    for (int u = 0; u < 4; ++u) { e[u] = __expf(pa[u] + pb[u]); sm[u] = e[u]; }
    #pragma unroll
    for (int mask = 16; mask; mask >>= 1)
      #pragma unroll
      for (int u = 0; u < 4; ++u) sm[u] += __shfl_xor(sm[u], mask);
    float cv[4];
    #pragma unroll
    for (int u = 0; u < 4; ++u) {
      float bv = l2 ? bw[u][lidx+1] : bw[u][lidx];
      cv[u] = (e[u] / sm[u]) * bv;
    }
    #pragma unroll
    for (int u = 0; u < 4; ++u) cv[u] += __shfl_xor(cv[u], 32);
    if (l2 == 0) {
      #pragma unroll
      for (int u = 0; u < 4; ++u)
        pout[(size_t)(b0+u)*I_ + i] = cv[u];
    }
  }
}

// ---------------------------------------------------------------- K4: reduce + body + head + confidence
__global__ __launch_bounds__(128) void k4_head(const float* __restrict__ partial,
    const float* __restrict__ best, const float* __restrict__ gammas,
    const float* __restrict__ body_w, const float* __restrict__ body_b,
    const float* __restrict__ head_w, const float* __restrict__ head_b,
    const float* __restrict__ conf, float* __restrict__ out)
{
  __shared__ float gavg[J_];
  __shared__ float cvred[4][I_];
  __shared__ float cvf[I_];
  const int b = blockIdx.x, tid = threadIdx.x;
  const int i = tid & 31, q = tid >> 5;
  if (tid < J_) {
    float gsum = 0.f;
    for (int l = 0; l < L_; ++l) {
      float g = gammas[tid*L_ + l];
      gsum += fminf(fmaxf(g, 0.f), 1.f);
    }
    gavg[tid] = gsum * (1.f / L_);
  }
  __syncthreads();

  float acc = 0.f;
  for (int s = q; s < 64; s += 4)
    acc += partial[((size_t)s*B_ + b)*I_ + i];

  #pragma unroll
  for (int u = 0; u < 2; ++u) {
    const int j = q + u*4;
    const float* bwv  = best + ((size_t)j*B_ + b)*L_;
    const float* wrow = body_w + (size_t)(j*I_ + i)*L_;
    float d0 = body_b[j*I_ + i], d1 = 0.f, d2 = 0.f, d3 = 0.f;
    #pragma unroll
    for (int c = 0; c < L_; c += 4) {
      d0 = fmaf(bwv[c+0], wrow[c+0], d0);
      d1 = fmaf(bwv[c+1], wrow[c+1], d1);
      d2 = fmaf(bwv[c+2], wrow[c+2], d2);
      d3 = fmaf(bwv[c+3], wrow[c+3], d3);
    }
    acc = fmaf(gavg[j], (d0 + d1) + (d2 + d3), acc);
  }
  cvred[q][i] = acc;
  __syncthreads();
  if (tid < I_)
    cvf[i] = cvred[0][i] + cvred[1][i] + cvred[2][i] + cvred[3][i];
  __syncthreads();
  float oacc = head_b[tid];
  #pragma unroll
  for (int i2 = 0; i2 < I_; ++i2) oacc = fmaf(cvf[i2], head_w[tid*I_ + i2], oacc);
  out[(size_t)b*O_ + tid] = conf[b] * oacc;
}

extern "C" void kernel_launch(void* const* d_in, const int* in_sizes, int n_in,
                              void* d_out, int out_size, void* d_ws, size_t ws_size,
                              hipStream_t stream) {
  const float* wm        = (const float*)d_in[0];
  const float* constants = (const float*)d_in[1];
  const float* gammas    = (const float*)d_in[2];
  const float* body_w    = (const float*)d_in[3];
  const float* body_b    = (const float*)d_in[4];
  const float* slot_w    = (const float*)d_in[5];
  const float* slot_b    = (const float*)d_in[6];
  const float* head_w    = (const float*)d_in[7];
  const float* head_b    = (const float*)d_in[8];
  float* out = (float*)d_out;

  float* ws      = (float*)d_ws;
  float* wcg     = ws;
  float* w1g     = wcg + J_*L_;
  float* Ag      = w1g + J_*L_;
  float* best    = Ag + 16;
  float* conf    = best + (size_t)J_*B_*L_;
  float* partial = conf + B_;
  float* bpart   = partial + (size_t)64*B_*I_;
  float* stats   = bpart + (size_t)H_*J_*B_*L_;

  hipLaunchKernelGGL(k0_prep, dim3(1), dim3(64), 0, stream,
                     constants, gammas, wcg, w1g, Ag);
  hipLaunchKernelGGL(k12_fused, dim3(B_, H_), dim3(256), 0, stream,
                     wm, wcg, w1g, Ag, bpart, stats);
  hipLaunchKernelGGL(k2b_combine, dim3(B_), dim3(128), 0, stream,
                     bpart, stats, best, conf);
  hipLaunchKernelGGL(k3_slot, dim3(16, 64), dim3(256), 0, stream,
                     slot_w, slot_b, best, partial);
  hipLaunchKernelGGL(k4_head, dim3(B_), dim3(128), 0, stream,
                     partial, best, gammas, body_w, body_b, head_w, head_b, conf, out);
}